// Round 4
// baseline (866.789 us; speedup 1.0000x reference)
//
#include <hip/hip_runtime.h>
#include <math.h>

// ---------------------------------------------------------------------------
// GCNSim: 2-layer GCN via dst-bucketed edge keys + barrier-free LDS-atomic agg
// NPB = 64 nodes per bucket; key = src (17b) | local_dst (6b) << 17
// hw1s/hw2s are pre-scaled by dis[row] so the edge loop is a single gather.
// agg1: keys staged in LDS, float4 gathers (8 lanes/edge), unroll-4, acc pad 33.
// ---------------------------------------------------------------------------

#define NPB 64
#define NB_PAD 2048
#define BATCH 16384
#define KCHUNK 2048

__global__ void zero_kernel(int* __restrict__ p, int c) {
    int i = blockIdx.x * 256 + threadIdx.x;
    if (i < c) p[i] = 0;
}

__global__ void needed_kernel(const int* __restrict__ nodes, int* __restrict__ needed, int nsel) {
    int i = blockIdx.x * 256 + threadIdx.x;
    if (i < nsel) needed[nodes[i]] = 1;
}

// ---- Pass A: per-bucket edge histogram (LDS-aggregated)
__global__ __launch_bounds__(256) void histA_kernel(const int* __restrict__ ei,
                                                    int* __restrict__ bhist, int nE, int nb) {
    __shared__ int h[NB_PAD];
    int tid = threadIdx.x;
    for (int t = tid; t < nb; t += 256) h[t] = 0;
    __syncthreads();
    int base = blockIdx.x * 4096;
    for (int t = tid; t < 4096; t += 256) {
        int e = base + t;
        if (e < nE) atomicAdd(&h[ei[nE + e] >> 6], 1);
    }
    __syncthreads();
    for (int t = tid; t < nb; t += 256) { int c = h[t]; if (c) atomicAdd(&bhist[t], c); }
}

// ---- Pass B: exclusive scan of bucket counts -> boffs[nb+1], gcur copy
__global__ __launch_bounds__(256) void scanB_kernel(const int* __restrict__ bhist,
                                                    int* __restrict__ boffs,
                                                    int* __restrict__ gcur, int nb) {
    int t = threadIdx.x;
    int v[8], s = 0;
    #pragma unroll
    for (int i = 0; i < 8; ++i) { int c = t * 8 + i; v[i] = (c < nb) ? bhist[c] : 0; s += v[i]; }
    int lane = t & 63, wid = t >> 6;
    int incl = s;
    for (int d = 1; d < 64; d <<= 1) { int u = __shfl_up(incl, (unsigned)d, 64); if (lane >= d) incl += u; }
    __shared__ int ws[4];
    if (lane == 63) ws[wid] = incl;
    __syncthreads();
    int add = 0;
    for (int w = 0; w < wid; ++w) add += ws[w];
    incl += add;
    int excl = incl - s;
    #pragma unroll
    for (int i = 0; i < 8; ++i) {
        int c = t * 8 + i;
        if (c < nb) { boffs[c] = excl; gcur[c] = excl; }
        excl += v[i];
    }
    if (t == 0) boffs[nb] = ws[0] + ws[1] + ws[2] + ws[3];
}

// ---- Pass C: batch-sorted scatter of packed keys into bucket regions
__global__ __launch_bounds__(256) void scatterC_kernel(const int* __restrict__ ei,
                                                       int* __restrict__ gcur,
                                                       int* __restrict__ keys, int nE, int nb) {
    __shared__ unsigned short sidx[BATCH];   // 32 KB
    __shared__ int hist[NB_PAD];
    __shared__ int lstart[NB_PAD];
    __shared__ int cursor[NB_PAD];
    __shared__ int gbase[NB_PAD];
    __shared__ int ws2[4];
    int tid = threadIdx.x;
    int base = blockIdx.x * BATCH;
    int cnt = nE - base; if (cnt > BATCH) cnt = BATCH;
    for (int t = tid; t < nb; t += 256) hist[t] = 0;
    __syncthreads();
    for (int t = tid; t < cnt; t += 256)
        atomicAdd(&hist[ei[nE + base + t] >> 6], 1);
    __syncthreads();
    {
        int v[8], s = 0;
        #pragma unroll
        for (int i = 0; i < 8; ++i) { int c = tid * 8 + i; v[i] = (c < nb) ? hist[c] : 0; s += v[i]; }
        int lane = tid & 63, wid = tid >> 6;
        int incl = s;
        for (int d = 1; d < 64; d <<= 1) { int u = __shfl_up(incl, (unsigned)d, 64); if (lane >= d) incl += u; }
        if (lane == 63) ws2[wid] = incl;
        __syncthreads();
        int add = 0;
        for (int w = 0; w < wid; ++w) add += ws2[w];
        incl += add;
        int excl = incl - s;
        #pragma unroll
        for (int i = 0; i < 8; ++i) {
            int c = tid * 8 + i;
            if (c < nb) { lstart[c] = excl; cursor[c] = excl; }
            excl += v[i];
        }
    }
    __syncthreads();
    for (int t = tid; t < nb; t += 256) {
        int c = hist[t];
        gbase[t] = c ? atomicAdd(&gcur[t], c) : 0;
    }
    for (int t = tid; t < cnt; t += 256) {
        int b = ei[nE + base + t] >> 6;
        int pos = atomicAdd(&cursor[b], 1);
        sidx[pos] = (unsigned short)t;
    }
    __syncthreads();
    for (int j = tid; j < cnt; j += 256) {
        int e = sidx[j];
        int d = ei[nE + base + e];
        int srcv = ei[base + e];
        int b = d >> 6;
        keys[gbase[b] + (j - lstart[b])] = srcv | ((d & 63) << 17);
    }
}

// ---- Pass C2: per-node degree (from grouped keys) -> dis
__global__ __launch_bounds__(256) void disC2_kernel(const int* __restrict__ keys,
                                                    const int* __restrict__ boffs,
                                                    float* __restrict__ dis, int n) {
    __shared__ int cnt[NPB];
    int tid = threadIdx.x, b = blockIdx.x;
    if (tid < NPB) cnt[tid] = 1;  // self-loop
    __syncthreads();
    int off = boffs[b], end = boffs[b + 1];
    for (int t = off + tid; t < end; t += 256)
        atomicAdd(&cnt[keys[t] >> 17], 1);
    __syncthreads();
    int node = b * NPB + tid;
    if (tid < NPB && node < n) dis[node] = rsqrtf((float)cnt[tid]);
}

// ---- hw1s = (x @ w1) * dis  [N,256]x[256,32] -> [N,32], 32 rows/block
__global__ __launch_bounds__(256) void hw1s_kernel(const float* __restrict__ x,
                                                   const float* __restrict__ w1,
                                                   const float* __restrict__ dis,
                                                   float* __restrict__ hw1s, int n) {
    __shared__ float w1s[256 * 32];   // 32 KB
    __shared__ float xs[32 * 256];    // 32 KB
    int tid = threadIdx.x;
    for (int t = tid * 4; t < 8192; t += 1024)
        *(float4*)&w1s[t] = *(const float4*)&w1[t];
    int row0 = blockIdx.x * 32;
    for (int t = tid; t < 2048; t += 256) {
        int r = t >> 6, c = (t & 63) * 4;
        int row = row0 + r;
        if (row < n) *(float4*)&xs[r * 256 + c] = *(const float4*)&x[(size_t)row * 256 + c];
        else *(float4*)&xs[r * 256 + c] = make_float4(0.f, 0.f, 0.f, 0.f);
    }
    __syncthreads();
    int k = tid & 31, rg = tid >> 5;          // 8 row-groups of 4 rows
    float a0 = 0.f, a1 = 0.f, a2 = 0.f, a3 = 0.f;
    #pragma unroll 4
    for (int c = 0; c < 256; c += 4) {
        float4 x0 = *(float4*)&xs[(rg * 4 + 0) * 256 + c];
        float4 x1 = *(float4*)&xs[(rg * 4 + 1) * 256 + c];
        float4 x2 = *(float4*)&xs[(rg * 4 + 2) * 256 + c];
        float4 x3 = *(float4*)&xs[(rg * 4 + 3) * 256 + c];
        float w0 = w1s[(c    ) * 32 + k];
        float w1v = w1s[(c + 1) * 32 + k];
        float w2v = w1s[(c + 2) * 32 + k];
        float w3 = w1s[(c + 3) * 32 + k];
        a0 += x0.x * w0 + x0.y * w1v + x0.z * w2v + x0.w * w3;
        a1 += x1.x * w0 + x1.y * w1v + x1.z * w2v + x1.w * w3;
        a2 += x2.x * w0 + x2.y * w1v + x2.z * w2v + x2.w * w3;
        a3 += x3.x * w0 + x3.y * w1v + x3.z * w2v + x3.w * w3;
    }
    int r0 = row0 + rg * 4;
    if (r0 + 0 < n) hw1s[(size_t)(r0 + 0) * 32 + k] = a0 * dis[r0 + 0];
    if (r0 + 1 < n) hw1s[(size_t)(r0 + 1) * 32 + k] = a1 * dis[r0 + 1];
    if (r0 + 2 < n) hw1s[(size_t)(r0 + 2) * 32 + k] = a2 * dis[r0 + 2];
    if (r0 + 3 < n) hw1s[(size_t)(r0 + 3) * 32 + k] = a3 * dis[r0 + 3];
}

// ---- Pass D: layer-1 aggregate. Keys LDS-staged; float4 gathers 8 lanes/edge;
//      unroll-4; padded acc (stride 33). Epilogue: ReLU + @w2 -> hw2s.
__global__ __launch_bounds__(256, 6) void agg1_kernel(const float* __restrict__ hw1s,
                                                      const float* __restrict__ dis,
                                                      const int* __restrict__ keys,
                                                      const int* __restrict__ boffs,
                                                      const float* __restrict__ b1,
                                                      const float* __restrict__ w2,
                                                      float* __restrict__ hw2s, int n) {
    __shared__ float acc[NPB * 33];   // 8.25 KB, stride-33 to spread banks
    __shared__ int ksh[KCHUNK];       // 8 KB
    __shared__ float w2s[512];
    __shared__ float b1s[32];
    int tid = threadIdx.x, b = blockIdx.x;
    for (int t = tid; t < NPB * 33; t += 256) acc[t] = 0.f;
    for (int t = tid; t < 512; t += 256) w2s[t] = w2[t];
    if (tid < 32) b1s[tid] = b1[tid];
    int off = boffs[b], end = boffs[b + 1];
    int q4 = (tid & 7) * 4;     // feature quad offset 0,4,...,28
    int es = tid >> 3;          // edge slot 0..31
    for (int cbase = off; cbase < end; cbase += KCHUNK) {
        int cnt = end - cbase; if (cnt > KCHUNK) cnt = KCHUNK;
        __syncthreads();   // previous chunk's readers done / first: init done
        for (int t = tid; t < cnt; t += 256) ksh[t] = keys[cbase + t];
        __syncthreads();
        int full = cnt & ~127;
        for (int base = 0; base < full; base += 128) {
            int k0 = ksh[base + es];
            int k1 = ksh[base + 32 + es];
            int k2 = ksh[base + 64 + es];
            int k3 = ksh[base + 96 + es];
            float4 v0 = *(const float4*)&hw1s[(size_t)(k0 & 0x1FFFF) * 32 + q4];
            float4 v1 = *(const float4*)&hw1s[(size_t)(k1 & 0x1FFFF) * 32 + q4];
            float4 v2 = *(const float4*)&hw1s[(size_t)(k2 & 0x1FFFF) * 32 + q4];
            float4 v3 = *(const float4*)&hw1s[(size_t)(k3 & 0x1FFFF) * 32 + q4];
            float* a0 = &acc[(k0 >> 17) * 33 + q4];
            float* a1 = &acc[(k1 >> 17) * 33 + q4];
            float* a2 = &acc[(k2 >> 17) * 33 + q4];
            float* a3 = &acc[(k3 >> 17) * 33 + q4];
            atomicAdd(a0 + 0, v0.x); atomicAdd(a0 + 1, v0.y);
            atomicAdd(a0 + 2, v0.z); atomicAdd(a0 + 3, v0.w);
            atomicAdd(a1 + 0, v1.x); atomicAdd(a1 + 1, v1.y);
            atomicAdd(a1 + 2, v1.z); atomicAdd(a1 + 3, v1.w);
            atomicAdd(a2 + 0, v2.x); atomicAdd(a2 + 1, v2.y);
            atomicAdd(a2 + 2, v2.z); atomicAdd(a2 + 3, v2.w);
            atomicAdd(a3 + 0, v3.x); atomicAdd(a3 + 1, v3.y);
            atomicAdd(a3 + 2, v3.z); atomicAdd(a3 + 3, v3.w);
        }
        for (int t = full + es; t < cnt; t += 32) {
            int kk = ksh[t];
            float4 v = *(const float4*)&hw1s[(size_t)(kk & 0x1FFFF) * 32 + q4];
            float* a = &acc[(kk >> 17) * 33 + q4];
            atomicAdd(a + 0, v.x); atomicAdd(a + 1, v.y);
            atomicAdd(a + 2, v.z); atomicAdd(a + 3, v.w);
        }
    }
    __syncthreads();
    int node0 = b * NPB;
    for (int t = tid; t < NPB * 32; t += 256) {
        int ld = t >> 5, kk = t & 31;
        int node = node0 + ld;
        if (node < n) {
            float dn = dis[node];
            float h1 = dn * (acc[ld * 33 + kk] + hw1s[(size_t)node * 32 + kk]) + b1s[kk];
            acc[ld * 33 + kk] = fmaxf(h1, 0.f);
        }
    }
    __syncthreads();
    for (int t = tid; t < NPB * 16; t += 256) {
        int ld = t >> 4, kk = t & 15;
        int node = node0 + ld;
        if (node < n) {
            float a = 0.f;
            #pragma unroll
            for (int cc = 0; cc < 32; ++cc) a += acc[ld * 33 + cc] * w2s[cc * 16 + kk];
            hw2s[(size_t)node * 16 + kk] = a * dis[node];
        }
    }
}

// ---- Pass E: layer-2 aggregate, selected-dst only, barrier-free -> h2
__global__ __launch_bounds__(256) void agg2_kernel(const float* __restrict__ hw2s,
                                                   const float* __restrict__ dis,
                                                   const int* __restrict__ keys,
                                                   const int* __restrict__ boffs,
                                                   const int* __restrict__ needed,
                                                   const float* __restrict__ b2,
                                                   float* __restrict__ h2, int n) {
    __shared__ float acc[NPB * 16];   // 4 KB
    __shared__ int fl[NPB];
    int tid = threadIdx.x, b = blockIdx.x;
    int node0 = b * NPB;
    if (tid < NPB) { int node = node0 + tid; fl[tid] = (node < n) ? needed[node] : 0; }
    for (int t = tid; t < NPB * 16; t += 256) acc[t] = 0.f;
    __syncthreads();
    int off = boffs[b], end = boffs[b + 1];
    int k = tid & 15, eslot = tid >> 4;   // 16 slots x 4-edge unroll = 64/round
    for (int base = off + eslot * 4; base < end; base += 64) {
        int c = end - base; if (c > 4) c = 4;
        #pragma unroll 4
        for (int j = 0; j < c; ++j) {
            int kk = keys[base + j];
            int ld = kk >> 17;
            if (fl[ld])
                atomicAdd(&acc[ld * 16 + k], hw2s[(kk & 0x1FFFF) * 16 + k]);
        }
    }
    __syncthreads();
    for (int t = tid; t < NPB * 16; t += 256) {
        int ld = t >> 4, kk = t & 15;
        int node = node0 + ld;
        if (node < n && fl[ld]) {
            float dn = dis[node];
            h2[node * 16 + kk] = dn * (acc[t] + hw2s[node * 16 + kk]) + b2[kk];
        }
    }
}

// ---- pairwise concat + MoE1 + MoE2 + log_softmax
__global__ __launch_bounds__(256) void pair_moe_kernel(const float* __restrict__ h2,
                                                       const int* __restrict__ nodes,
                                                       const float* __restrict__ gate1_w,
                                                       const float* __restrict__ e1_w,
                                                       const float* __restrict__ e1_b,
                                                       const float* __restrict__ gate2_w,
                                                       const float* __restrict__ e2_w,
                                                       const float* __restrict__ e2_b,
                                                       float* __restrict__ out1,
                                                       float* __restrict__ out2, int M) {
    __shared__ float hjs[50 * 16];
    __shared__ float g1s[32 * 4];
    __shared__ float e1ws[4 * 32 * 16];
    __shared__ float e1bs[4 * 16];
    __shared__ float g2s[16 * 4];
    __shared__ float e2ws[4 * 16 * 2];
    __shared__ float e2bs[4 * 2];
    int tid = threadIdx.x;
    for (int t = tid; t < 800; t += 256) { int j = t >> 4, c = t & 15; hjs[t] = h2[nodes[j] * 16 + c]; }
    for (int t = tid; t < 128; t += 256) g1s[t] = gate1_w[t];
    for (int t = tid; t < 2048; t += 256) e1ws[t] = e1_w[t];
    for (int t = tid; t < 64; t += 256) e1bs[t] = e1_b[t];
    for (int t = tid; t < 64; t += 256) g2s[t] = gate2_w[t];
    for (int t = tid; t < 128; t += 256) e2ws[t] = e2_w[t];
    if (tid < 8) e2bs[tid] = e2_b[tid];
    __syncthreads();

    int m = blockIdx.x * 256 + tid;
    if (m >= M) return;
    int i = m / 50, j = m - i * 50;

    float xs[32];
    int ni = nodes[i];
    float4 a0 = *(const float4*)&h2[ni * 16];
    float4 a1 = *(const float4*)&h2[ni * 16 + 4];
    float4 a2 = *(const float4*)&h2[ni * 16 + 8];
    float4 a3 = *(const float4*)&h2[ni * 16 + 12];
    xs[0]=a0.x; xs[1]=a0.y; xs[2]=a0.z; xs[3]=a0.w;
    xs[4]=a1.x; xs[5]=a1.y; xs[6]=a1.z; xs[7]=a1.w;
    xs[8]=a2.x; xs[9]=a2.y; xs[10]=a2.z; xs[11]=a2.w;
    xs[12]=a3.x; xs[13]=a3.y; xs[14]=a3.z; xs[15]=a3.w;
    #pragma unroll
    for (int c = 0; c < 16; ++c) xs[16 + c] = hjs[j * 16 + c];

    #pragma unroll
    for (int c = 0; c < 32; c += 4)
        *(float4*)&out2[(size_t)m * 32 + c] = make_float4(xs[c], xs[c+1], xs[c+2], xs[c+3]);

    float g[4] = {0.f, 0.f, 0.f, 0.f};
    #pragma unroll
    for (int c = 0; c < 32; ++c) {
        float xv = xs[c];
        #pragma unroll
        for (int e = 0; e < 4; ++e) g[e] += xv * g1s[c * 4 + e];
    }
    int idx = 0; float best = g[0];
    #pragma unroll
    for (int e = 1; e < 4; ++e) if (g[e] > best) { best = g[e]; idx = e; }
    float z[16];
    #pragma unroll
    for (int o = 0; o < 16; ++o) {
        float a = e1bs[idx * 16 + o];
        #pragma unroll
        for (int c = 0; c < 32; ++c) a += xs[c] * e1ws[(idx * 32 + c) * 16 + o];
        z[o] = fmaxf(a, 0.f);
    }

    float g2[4] = {0.f, 0.f, 0.f, 0.f};
    #pragma unroll
    for (int c = 0; c < 16; ++c) {
        float zv = z[c];
        #pragma unroll
        for (int e = 0; e < 4; ++e) g2[e] += zv * g2s[c * 4 + e];
    }
    int idx2 = 0; float best2 = g2[0];
    #pragma unroll
    for (int e = 1; e < 4; ++e) if (g2[e] > best2) { best2 = g2[e]; idx2 = e; }
    float z2[2];
    #pragma unroll
    for (int o = 0; o < 2; ++o) {
        float a = e2bs[idx2 * 2 + o];
        #pragma unroll
        for (int c = 0; c < 16; ++c) a += z[c] * e2ws[(idx2 * 16 + c) * 2 + o];
        z2[o] = a;
    }

    float mx = fmaxf(z2[0], z2[1]);
    float l = logf(expf(z2[0] - mx) + expf(z2[1] - mx));
    out1[(size_t)m * 2 + 0] = z2[0] - mx - l;
    out1[(size_t)m * 2 + 1] = z2[1] - mx - l;
}

extern "C" void kernel_launch(void* const* d_in, const int* in_sizes, int n_in,
                              void* d_out, int out_size, void* d_ws, size_t ws_size,
                              hipStream_t stream) {
    const float* x       = (const float*)d_in[0];
    const float* w1      = (const float*)d_in[1];
    const float* b1      = (const float*)d_in[2];
    const float* w2      = (const float*)d_in[3];
    const float* b2      = (const float*)d_in[4];
    const float* gate1_w = (const float*)d_in[5];
    const float* e1_w    = (const float*)d_in[6];
    const float* e1_b    = (const float*)d_in[7];
    const float* gate2_w = (const float*)d_in[8];
    const float* e2_w    = (const float*)d_in[9];
    const float* e2_b    = (const float*)d_in[10];
    const int*   ei      = (const int*)d_in[11];
    const int*   nodes   = (const int*)d_in[12];

    const int n    = in_sizes[0] / 256;      // 100000
    const int nE   = in_sizes[11] / 2;       // 3200000
    const int nsel = in_sizes[12];           // 4096
    const int M    = nsel * 50;              // 204800
    const int nb   = (n + NPB - 1) / NPB;    // 1563

    size_t off = 0;
    auto alloc = [&](size_t bytes) -> void* {
        void* p = (char*)d_ws + off;
        off += (bytes + 255) & ~(size_t)255;
        return p;
    };
    float* dis    = (float*)alloc((size_t)n * 4);
    int*   needed = (int*)alloc((size_t)n * 4);
    int*   bhist  = (int*)alloc((size_t)nb * 4);
    int*   boffs  = (int*)alloc((size_t)(nb + 1) * 4);
    int*   gcur   = (int*)alloc((size_t)nb * 4);
    int*   keys   = (int*)alloc((size_t)nE * 4);
    float* hw1s   = (float*)alloc((size_t)n * 32 * 4);
    float* hw2s   = (float*)alloc((size_t)n * 16 * 4);
    float* h2     = hw1s;  // hw1s dead after agg1; reuse as h2
    if (off > ws_size) return;

    float* out1 = (float*)d_out;              // [M,2]
    float* out2 = out1 + (size_t)M * 2;       // [M,32]

    zero_kernel<<<(n + 255) / 256, 256, 0, stream>>>(needed, n);
    zero_kernel<<<(nb + 255) / 256, 256, 0, stream>>>(bhist, nb);
    needed_kernel<<<(nsel + 255) / 256, 256, 0, stream>>>(nodes, needed, nsel);
    histA_kernel<<<(nE + 4095) / 4096, 256, 0, stream>>>(ei, bhist, nE, nb);
    scanB_kernel<<<1, 256, 0, stream>>>(bhist, boffs, gcur, nb);
    scatterC_kernel<<<(nE + BATCH - 1) / BATCH, 256, 0, stream>>>(ei, gcur, keys, nE, nb);
    disC2_kernel<<<nb, 256, 0, stream>>>(keys, boffs, dis, n);
    hw1s_kernel<<<(n + 31) / 32, 256, 0, stream>>>(x, w1, dis, hw1s, n);
    agg1_kernel<<<nb, 256, 0, stream>>>(hw1s, dis, keys, boffs, b1, w2, hw2s, n);
    agg2_kernel<<<nb, 256, 0, stream>>>(hw2s, dis, keys, boffs, needed, b2, h2, n);
    pair_moe_kernel<<<(M + 255) / 256, 256, 0, stream>>>(h2, nodes, gate1_w, e1_w, e1_b,
                                                         gate2_w, e2_w, e2_b, out1, out2, M);
}

// Round 5
// 864.765 us; speedup vs baseline: 1.0023x; 1.0023x over previous
//
#include <hip/hip_runtime.h>
#include <hip/hip_fp16.h>
#include <math.h>

// ---------------------------------------------------------------------------
// GCNSim: 2-layer GCN via dst-bucketed edge keys + LDS-atomic aggregation.
// NPB = 64 nodes per bucket; key = src (17b) | local_dst (6b) << 17
// Layer-1 projection stored as TWO fp16 feature-slabs of 3.2 MB each so the
// random per-edge gather working set is L2-resident (4 MB per XCD).
// ---------------------------------------------------------------------------

#define NPB 64
#define NB_PAD 2048
#define BATCH 16384
#define KCHUNK 2048

__global__ void zero_kernel(int* __restrict__ p, int c) {
    int i = blockIdx.x * 256 + threadIdx.x;
    if (i < c) p[i] = 0;
}

__global__ void needed_kernel(const int* __restrict__ nodes, int* __restrict__ needed, int nsel) {
    int i = blockIdx.x * 256 + threadIdx.x;
    if (i < nsel) needed[nodes[i]] = 1;
}

// ---- Pass A: per-bucket edge histogram (LDS-aggregated)
__global__ __launch_bounds__(256) void histA_kernel(const int* __restrict__ ei,
                                                    int* __restrict__ bhist, int nE, int nb) {
    __shared__ int h[NB_PAD];
    int tid = threadIdx.x;
    for (int t = tid; t < nb; t += 256) h[t] = 0;
    __syncthreads();
    int base = blockIdx.x * 4096;
    for (int t = tid; t < 4096; t += 256) {
        int e = base + t;
        if (e < nE) atomicAdd(&h[ei[nE + e] >> 6], 1);
    }
    __syncthreads();
    for (int t = tid; t < nb; t += 256) { int c = h[t]; if (c) atomicAdd(&bhist[t], c); }
}

// ---- Pass B: exclusive scan of bucket counts -> boffs[nb+1], gcur copy
__global__ __launch_bounds__(256) void scanB_kernel(const int* __restrict__ bhist,
                                                    int* __restrict__ boffs,
                                                    int* __restrict__ gcur, int nb) {
    int t = threadIdx.x;
    int v[8], s = 0;
    #pragma unroll
    for (int i = 0; i < 8; ++i) { int c = t * 8 + i; v[i] = (c < nb) ? bhist[c] : 0; s += v[i]; }
    int lane = t & 63, wid = t >> 6;
    int incl = s;
    for (int d = 1; d < 64; d <<= 1) { int u = __shfl_up(incl, (unsigned)d, 64); if (lane >= d) incl += u; }
    __shared__ int ws[4];
    if (lane == 63) ws[wid] = incl;
    __syncthreads();
    int add = 0;
    for (int w = 0; w < wid; ++w) add += ws[w];
    incl += add;
    int excl = incl - s;
    #pragma unroll
    for (int i = 0; i < 8; ++i) {
        int c = t * 8 + i;
        if (c < nb) { boffs[c] = excl; gcur[c] = excl; }
        excl += v[i];
    }
    if (t == 0) boffs[nb] = ws[0] + ws[1] + ws[2] + ws[3];
}

// ---- Pass C: batch-sorted scatter of packed keys into bucket regions
__global__ __launch_bounds__(256) void scatterC_kernel(const int* __restrict__ ei,
                                                       int* __restrict__ gcur,
                                                       int* __restrict__ keys, int nE, int nb) {
    __shared__ unsigned short sidx[BATCH];   // 32 KB
    __shared__ int hist[NB_PAD];
    __shared__ int lstart[NB_PAD];
    __shared__ int cursor[NB_PAD];
    __shared__ int gbase[NB_PAD];
    __shared__ int ws2[4];
    int tid = threadIdx.x;
    int base = blockIdx.x * BATCH;
    int cnt = nE - base; if (cnt > BATCH) cnt = BATCH;
    for (int t = tid; t < nb; t += 256) hist[t] = 0;
    __syncthreads();
    for (int t = tid; t < cnt; t += 256)
        atomicAdd(&hist[ei[nE + base + t] >> 6], 1);
    __syncthreads();
    {
        int v[8], s = 0;
        #pragma unroll
        for (int i = 0; i < 8; ++i) { int c = tid * 8 + i; v[i] = (c < nb) ? hist[c] : 0; s += v[i]; }
        int lane = tid & 63, wid = tid >> 6;
        int incl = s;
        for (int d = 1; d < 64; d <<= 1) { int u = __shfl_up(incl, (unsigned)d, 64); if (lane >= d) incl += u; }
        if (lane == 63) ws2[wid] = incl;
        __syncthreads();
        int add = 0;
        for (int w = 0; w < wid; ++w) add += ws2[w];
        incl += add;
        int excl = incl - s;
        #pragma unroll
        for (int i = 0; i < 8; ++i) {
            int c = tid * 8 + i;
            if (c < nb) { lstart[c] = excl; cursor[c] = excl; }
            excl += v[i];
        }
    }
    __syncthreads();
    for (int t = tid; t < nb; t += 256) {
        int c = hist[t];
        gbase[t] = c ? atomicAdd(&gcur[t], c) : 0;
    }
    for (int t = tid; t < cnt; t += 256) {
        int b = ei[nE + base + t] >> 6;
        int pos = atomicAdd(&cursor[b], 1);
        sidx[pos] = (unsigned short)t;
    }
    __syncthreads();
    for (int j = tid; j < cnt; j += 256) {
        int e = sidx[j];
        int d = ei[nE + base + e];
        int srcv = ei[base + e];
        int b = d >> 6;
        keys[gbase[b] + (j - lstart[b])] = srcv | ((d & 63) << 17);
    }
}

// ---- Pass C2: per-node degree (from grouped keys) -> dis
__global__ __launch_bounds__(256) void disC2_kernel(const int* __restrict__ keys,
                                                    const int* __restrict__ boffs,
                                                    float* __restrict__ dis, int n) {
    __shared__ int cnt[NPB];
    int tid = threadIdx.x, b = blockIdx.x;
    if (tid < NPB) cnt[tid] = 1;  // self-loop
    __syncthreads();
    int off = boffs[b], end = boffs[b + 1];
    for (int t = off + tid; t < end; t += 256)
        atomicAdd(&cnt[keys[t] >> 17], 1);
    __syncthreads();
    int node = b * NPB + tid;
    if (tid < NPB && node < n) dis[node] = rsqrtf((float)cnt[tid]);
}

// ---- hw1 slabs: A = fp16[(x@w1)*dis][:, 0:16], B = [:, 16:32]
__global__ __launch_bounds__(256) void hw1s_kernel(const float* __restrict__ x,
                                                   const float* __restrict__ w1,
                                                   const float* __restrict__ dis,
                                                   __half* __restrict__ hw1A,
                                                   __half* __restrict__ hw1B, int n) {
    __shared__ float w1s[256 * 32];   // 32 KB
    __shared__ float xs[32 * 256];    // 32 KB
    int tid = threadIdx.x;
    for (int t = tid * 4; t < 8192; t += 1024)
        *(float4*)&w1s[t] = *(const float4*)&w1[t];
    int row0 = blockIdx.x * 32;
    for (int t = tid; t < 2048; t += 256) {
        int r = t >> 6, c = (t & 63) * 4;
        int row = row0 + r;
        if (row < n) *(float4*)&xs[r * 256 + c] = *(const float4*)&x[(size_t)row * 256 + c];
        else *(float4*)&xs[r * 256 + c] = make_float4(0.f, 0.f, 0.f, 0.f);
    }
    __syncthreads();
    int k = tid & 31, rg = tid >> 5;          // 8 row-groups of 4 rows
    float a0 = 0.f, a1 = 0.f, a2 = 0.f, a3 = 0.f;
    #pragma unroll 4
    for (int c = 0; c < 256; c += 4) {
        float4 x0 = *(float4*)&xs[(rg * 4 + 0) * 256 + c];
        float4 x1 = *(float4*)&xs[(rg * 4 + 1) * 256 + c];
        float4 x2 = *(float4*)&xs[(rg * 4 + 2) * 256 + c];
        float4 x3 = *(float4*)&xs[(rg * 4 + 3) * 256 + c];
        float w0 = w1s[(c    ) * 32 + k];
        float w1v = w1s[(c + 1) * 32 + k];
        float w2v = w1s[(c + 2) * 32 + k];
        float w3 = w1s[(c + 3) * 32 + k];
        a0 += x0.x * w0 + x0.y * w1v + x0.z * w2v + x0.w * w3;
        a1 += x1.x * w0 + x1.y * w1v + x1.z * w2v + x1.w * w3;
        a2 += x2.x * w0 + x2.y * w1v + x2.z * w2v + x2.w * w3;
        a3 += x3.x * w0 + x3.y * w1v + x3.z * w2v + x3.w * w3;
    }
    int r0 = row0 + rg * 4;
    __half* dst = (k < 16) ? hw1A : hw1B;
    int kf = k & 15;
    if (r0 + 0 < n) dst[(size_t)(r0 + 0) * 16 + kf] = __float2half(a0 * dis[r0 + 0]);
    if (r0 + 1 < n) dst[(size_t)(r0 + 1) * 16 + kf] = __float2half(a1 * dis[r0 + 1]);
    if (r0 + 2 < n) dst[(size_t)(r0 + 2) * 16 + kf] = __float2half(a2 * dis[r0 + 2]);
    if (r0 + 3 < n) dst[(size_t)(r0 + 3) * 16 + kf] = __float2half(a3 * dis[r0 + 3]);
}

// ---- Pass D: layer-1 aggregate. Keys LDS-staged; two fp16 slab passes so the
//      gather working set (3.2 MB) is L2-resident. Epilogue: ReLU + @w2 -> hw2s.
__global__ __launch_bounds__(256, 6) void agg1_kernel(const __half* __restrict__ hw1A,
                                                      const __half* __restrict__ hw1B,
                                                      const float* __restrict__ dis,
                                                      const int* __restrict__ keys,
                                                      const int* __restrict__ boffs,
                                                      const float* __restrict__ b1,
                                                      const float* __restrict__ w2,
                                                      float* __restrict__ hw2s, int n) {
    __shared__ float acc[NPB * 33];   // 8.25 KB, stride 33 (=1 mod 32 banks)
    __shared__ int ksh[KCHUNK];       // 8 KB
    __shared__ float w2s[512];
    __shared__ float b1s[32];
    int tid = threadIdx.x, b = blockIdx.x;
    for (int t = tid; t < NPB * 33; t += 256) acc[t] = 0.f;
    for (int t = tid; t < 512; t += 256) w2s[t] = w2[t];
    if (tid < 32) b1s[tid] = b1[tid];
    int off = boffs[b], end = boffs[b + 1];
    int h = tid & 1;            // half-row selector (8 halves = 16 B each)
    int es = tid >> 1;          // edge slot 0..127

#define GATHER_ATOMIC(slab4, kk) { \
        union { float4 f4; __half2 hp[4]; } u; \
        u.f4 = slab4[(size_t)((kk) & 0x1FFFF) * 2 + h]; \
        float* a = &acc[((kk) >> 17) * 33 + poff]; \
        float2 f; \
        f = __half22float2(u.hp[0]); atomicAdd(a + 0, f.x); atomicAdd(a + 1, f.y); \
        f = __half22float2(u.hp[1]); atomicAdd(a + 2, f.x); atomicAdd(a + 3, f.y); \
        f = __half22float2(u.hp[2]); atomicAdd(a + 4, f.x); atomicAdd(a + 5, f.y); \
        f = __half22float2(u.hp[3]); atomicAdd(a + 6, f.x); atomicAdd(a + 7, f.y); \
    }

    for (int cbase = off; cbase < end; cbase += KCHUNK) {
        int cnt = end - cbase; if (cnt > KCHUNK) cnt = KCHUNK;
        __syncthreads();   // prior readers of ksh done (first iter: init done)
        for (int t = tid; t < cnt; t += 256) ksh[t] = keys[cbase + t];
        __syncthreads();
        #pragma unroll
        for (int pass = 0; pass < 2; ++pass) {
            const float4* slab4 = (const float4*)(pass ? hw1B : hw1A);
            int poff = pass * 16 + h * 8;
            int eb = 0;
            for (; eb + 512 <= cnt; eb += 512) {
                int kA = ksh[eb + es];
                int kB = ksh[eb + 128 + es];
                int kC = ksh[eb + 256 + es];
                int kD = ksh[eb + 384 + es];
                GATHER_ATOMIC(slab4, kA);
                GATHER_ATOMIC(slab4, kB);
                GATHER_ATOMIC(slab4, kC);
                GATHER_ATOMIC(slab4, kD);
            }
            for (; eb + 128 <= cnt; eb += 128) {
                int kA = ksh[eb + es];
                GATHER_ATOMIC(slab4, kA);
            }
            if (eb + es < cnt) {
                int kA = ksh[eb + es];
                GATHER_ATOMIC(slab4, kA);
            }
        }
    }
#undef GATHER_ATOMIC
    __syncthreads();
    int node0 = b * NPB;
    for (int t = tid; t < NPB * 32; t += 256) {
        int ld = t >> 5, kk = t & 31;
        int node = node0 + ld;
        if (node < n) {
            float dn = dis[node];
            float self = (kk < 16) ? __half2float(hw1A[(size_t)node * 16 + kk])
                                   : __half2float(hw1B[(size_t)node * 16 + (kk - 16)]);
            float h1 = dn * (acc[ld * 33 + kk] + self) + b1s[kk];
            acc[ld * 33 + kk] = fmaxf(h1, 0.f);
        }
    }
    __syncthreads();
    for (int t = tid; t < NPB * 16; t += 256) {
        int ld = t >> 4, kk = t & 15;
        int node = node0 + ld;
        if (node < n) {
            float a = 0.f;
            #pragma unroll
            for (int cc = 0; cc < 32; ++cc) a += acc[ld * 33 + cc] * w2s[cc * 16 + kk];
            hw2s[(size_t)node * 16 + kk] = a * dis[node];
        }
    }
}

// ---- Pass E: layer-2 aggregate, selected-dst only -> h2
__global__ __launch_bounds__(256) void agg2_kernel(const float* __restrict__ hw2s,
                                                   const float* __restrict__ dis,
                                                   const int* __restrict__ keys,
                                                   const int* __restrict__ boffs,
                                                   const int* __restrict__ needed,
                                                   const float* __restrict__ b2,
                                                   float* __restrict__ h2, int n) {
    __shared__ float acc[NPB * 16];   // 4 KB
    __shared__ int fl[NPB];
    int tid = threadIdx.x, b = blockIdx.x;
    int node0 = b * NPB;
    if (tid < NPB) { int node = node0 + tid; fl[tid] = (node < n) ? needed[node] : 0; }
    for (int t = tid; t < NPB * 16; t += 256) acc[t] = 0.f;
    __syncthreads();
    int off = boffs[b], end = boffs[b + 1];
    int k = tid & 15, eslot = tid >> 4;   // 16 slots x 4-edge unroll = 64/round
    for (int base = off + eslot * 4; base < end; base += 64) {
        int c = end - base; if (c > 4) c = 4;
        #pragma unroll 4
        for (int j = 0; j < c; ++j) {
            int kk = keys[base + j];
            int ld = kk >> 17;
            if (fl[ld])
                atomicAdd(&acc[ld * 16 + k], hw2s[(kk & 0x1FFFF) * 16 + k]);
        }
    }
    __syncthreads();
    for (int t = tid; t < NPB * 16; t += 256) {
        int ld = t >> 4, kk = t & 15;
        int node = node0 + ld;
        if (node < n && fl[ld]) {
            float dn = dis[node];
            h2[node * 16 + kk] = dn * (acc[t] + hw2s[node * 16 + kk]) + b2[kk];
        }
    }
}

// ---- pairwise concat + MoE1 + MoE2 + log_softmax
__global__ __launch_bounds__(256) void pair_moe_kernel(const float* __restrict__ h2,
                                                       const int* __restrict__ nodes,
                                                       const float* __restrict__ gate1_w,
                                                       const float* __restrict__ e1_w,
                                                       const float* __restrict__ e1_b,
                                                       const float* __restrict__ gate2_w,
                                                       const float* __restrict__ e2_w,
                                                       const float* __restrict__ e2_b,
                                                       float* __restrict__ out1,
                                                       float* __restrict__ out2, int M) {
    __shared__ float hjs[50 * 16];
    __shared__ float g1s[32 * 4];
    __shared__ float e1ws[4 * 32 * 16];
    __shared__ float e1bs[4 * 16];
    __shared__ float g2s[16 * 4];
    __shared__ float e2ws[4 * 16 * 2];
    __shared__ float e2bs[4 * 2];
    int tid = threadIdx.x;
    for (int t = tid; t < 800; t += 256) { int j = t >> 4, c = t & 15; hjs[t] = h2[nodes[j] * 16 + c]; }
    for (int t = tid; t < 128; t += 256) g1s[t] = gate1_w[t];
    for (int t = tid; t < 2048; t += 256) e1ws[t] = e1_w[t];
    for (int t = tid; t < 64; t += 256) e1bs[t] = e1_b[t];
    for (int t = tid; t < 64; t += 256) g2s[t] = gate2_w[t];
    for (int t = tid; t < 128; t += 256) e2ws[t] = e2_w[t];
    if (tid < 8) e2bs[tid] = e2_b[tid];
    __syncthreads();

    int m = blockIdx.x * 256 + tid;
    if (m >= M) return;
    int i = m / 50, j = m - i * 50;

    float xs[32];
    int ni = nodes[i];
    float4 a0 = *(const float4*)&h2[ni * 16];
    float4 a1 = *(const float4*)&h2[ni * 16 + 4];
    float4 a2 = *(const float4*)&h2[ni * 16 + 8];
    float4 a3 = *(const float4*)&h2[ni * 16 + 12];
    xs[0]=a0.x; xs[1]=a0.y; xs[2]=a0.z; xs[3]=a0.w;
    xs[4]=a1.x; xs[5]=a1.y; xs[6]=a1.z; xs[7]=a1.w;
    xs[8]=a2.x; xs[9]=a2.y; xs[10]=a2.z; xs[11]=a2.w;
    xs[12]=a3.x; xs[13]=a3.y; xs[14]=a3.z; xs[15]=a3.w;
    #pragma unroll
    for (int c = 0; c < 16; ++c) xs[16 + c] = hjs[j * 16 + c];

    #pragma unroll
    for (int c = 0; c < 32; c += 4)
        *(float4*)&out2[(size_t)m * 32 + c] = make_float4(xs[c], xs[c+1], xs[c+2], xs[c+3]);

    float g[4] = {0.f, 0.f, 0.f, 0.f};
    #pragma unroll
    for (int c = 0; c < 32; ++c) {
        float xv = xs[c];
        #pragma unroll
        for (int e = 0; e < 4; ++e) g[e] += xv * g1s[c * 4 + e];
    }
    int idx = 0; float best = g[0];
    #pragma unroll
    for (int e = 1; e < 4; ++e) if (g[e] > best) { best = g[e]; idx = e; }
    float z[16];
    #pragma unroll
    for (int o = 0; o < 16; ++o) {
        float a = e1bs[idx * 16 + o];
        #pragma unroll
        for (int c = 0; c < 32; ++c) a += xs[c] * e1ws[(idx * 32 + c) * 16 + o];
        z[o] = fmaxf(a, 0.f);
    }

    float g2[4] = {0.f, 0.f, 0.f, 0.f};
    #pragma unroll
    for (int c = 0; c < 16; ++c) {
        float zv = z[c];
        #pragma unroll
        for (int e = 0; e < 4; ++e) g2[e] += zv * g2s[c * 4 + e];
    }
    int idx2 = 0; float best2 = g2[0];
    #pragma unroll
    for (int e = 1; e < 4; ++e) if (g2[e] > best2) { best2 = g2[e]; idx2 = e; }
    float z2[2];
    #pragma unroll
    for (int o = 0; o < 2; ++o) {
        float a = e2bs[idx2 * 2 + o];
        #pragma unroll
        for (int c = 0; c < 16; ++c) a += z[c] * e2ws[(idx2 * 16 + c) * 2 + o];
        z2[o] = a;
    }

    float mx = fmaxf(z2[0], z2[1]);
    float l = logf(expf(z2[0] - mx) + expf(z2[1] - mx));
    out1[(size_t)m * 2 + 0] = z2[0] - mx - l;
    out1[(size_t)m * 2 + 1] = z2[1] - mx - l;
}

extern "C" void kernel_launch(void* const* d_in, const int* in_sizes, int n_in,
                              void* d_out, int out_size, void* d_ws, size_t ws_size,
                              hipStream_t stream) {
    const float* x       = (const float*)d_in[0];
    const float* w1      = (const float*)d_in[1];
    const float* b1      = (const float*)d_in[2];
    const float* w2      = (const float*)d_in[3];
    const float* b2      = (const float*)d_in[4];
    const float* gate1_w = (const float*)d_in[5];
    const float* e1_w    = (const float*)d_in[6];
    const float* e1_b    = (const float*)d_in[7];
    const float* gate2_w = (const float*)d_in[8];
    const float* e2_w    = (const float*)d_in[9];
    const float* e2_b    = (const float*)d_in[10];
    const int*   ei      = (const int*)d_in[11];
    const int*   nodes   = (const int*)d_in[12];

    const int n    = in_sizes[0] / 256;      // 100000
    const int nE   = in_sizes[11] / 2;       // 3200000
    const int nsel = in_sizes[12];           // 4096
    const int M    = nsel * 50;              // 204800
    const int nb   = (n + NPB - 1) / NPB;    // 1563

    size_t off = 0;
    auto alloc = [&](size_t bytes) -> void* {
        void* p = (char*)d_ws + off;
        off += (bytes + 255) & ~(size_t)255;
        return p;
    };
    float*  dis    = (float*)alloc((size_t)n * 4);
    int*    needed = (int*)alloc((size_t)n * 4);
    int*    bhist  = (int*)alloc((size_t)nb * 4);
    int*    boffs  = (int*)alloc((size_t)(nb + 1) * 4);
    int*    gcur   = (int*)alloc((size_t)nb * 4);
    int*    keys   = (int*)alloc((size_t)nE * 4);
    __half* hw1A   = (__half*)alloc((size_t)n * 16 * 2);
    __half* hw1B   = (__half*)alloc((size_t)n * 16 * 2);
    float*  hw2s   = (float*)alloc((size_t)n * 16 * 4);
    float*  h2     = (float*)alloc((size_t)n * 16 * 4);
    if (off > ws_size) return;

    float* out1 = (float*)d_out;              // [M,2]
    float* out2 = out1 + (size_t)M * 2;       // [M,32]

    zero_kernel<<<(n + 255) / 256, 256, 0, stream>>>(needed, n);
    zero_kernel<<<(nb + 255) / 256, 256, 0, stream>>>(bhist, nb);
    needed_kernel<<<(nsel + 255) / 256, 256, 0, stream>>>(nodes, needed, nsel);
    histA_kernel<<<(nE + 4095) / 4096, 256, 0, stream>>>(ei, bhist, nE, nb);
    scanB_kernel<<<1, 256, 0, stream>>>(bhist, boffs, gcur, nb);
    scatterC_kernel<<<(nE + BATCH - 1) / BATCH, 256, 0, stream>>>(ei, gcur, keys, nE, nb);
    disC2_kernel<<<nb, 256, 0, stream>>>(keys, boffs, dis, n);
    hw1s_kernel<<<(n + 31) / 32, 256, 0, stream>>>(x, w1, dis, hw1A, hw1B, n);
    agg1_kernel<<<nb, 256, 0, stream>>>(hw1A, hw1B, dis, keys, boffs, b1, w2, hw2s, n);
    agg2_kernel<<<nb, 256, 0, stream>>>(hw2s, dis, keys, boffs, needed, b2, h2, n);
    pair_moe_kernel<<<(M + 255) / 256, 256, 0, stream>>>(h2, nodes, gate1_w, e1_w, e1_b,
                                                         gate2_w, e2_w, e2_b, out1, out2, M);
}

// Round 6
// 831.495 us; speedup vs baseline: 1.0424x; 1.0400x over previous
//
#include <hip/hip_runtime.h>
#include <hip/hip_fp16.h>
#include <math.h>

// ---------------------------------------------------------------------------
// GCNSim: 2-layer GCN via dst-bucketed edge keys + async LDS-staged gathers.
// key = src (17b) | local_dst (6b) << 17 ; NPB = 64 nodes per bucket.
// hw1h = fp16[(x@w1)*dis] as [N][32] (64B rows); per-edge gather is one line.
// agg1 uses global_load_lds (async, no VGPR landing) => high MLP.
// ---------------------------------------------------------------------------

#define NPB 64
#define NB_PAD 2048
#define BATCH 16384

__device__ __forceinline__ void gload16(const void* g, void* l) {
    __builtin_amdgcn_global_load_lds((__attribute__((address_space(1))) void*)g,
                                     (__attribute__((address_space(3))) void*)l,
                                     16, 0, 0);
}

__global__ void zero_kernel(int* __restrict__ p, int c) {
    int i = blockIdx.x * 256 + threadIdx.x;
    if (i < c) p[i] = 0;
}

__global__ void needed_kernel(const int* __restrict__ nodes, int* __restrict__ needed, int nsel) {
    int i = blockIdx.x * 256 + threadIdx.x;
    if (i < nsel) needed[nodes[i]] = 1;
}

// ---- Pass A: per-bucket edge histogram (LDS-aggregated)
__global__ __launch_bounds__(256) void histA_kernel(const int* __restrict__ ei,
                                                    int* __restrict__ bhist, int nE, int nb) {
    __shared__ int h[NB_PAD];
    int tid = threadIdx.x;
    for (int t = tid; t < nb; t += 256) h[t] = 0;
    __syncthreads();
    int base = blockIdx.x * 4096;
    for (int t = tid; t < 4096; t += 256) {
        int e = base + t;
        if (e < nE) atomicAdd(&h[ei[nE + e] >> 6], 1);
    }
    __syncthreads();
    for (int t = tid; t < nb; t += 256) { int c = h[t]; if (c) atomicAdd(&bhist[t], c); }
}

// ---- Pass B: exclusive scan of bucket counts -> boffs[nb+1], gcur copy
__global__ __launch_bounds__(256) void scanB_kernel(const int* __restrict__ bhist,
                                                    int* __restrict__ boffs,
                                                    int* __restrict__ gcur, int nb) {
    int t = threadIdx.x;
    int v[8], s = 0;
    #pragma unroll
    for (int i = 0; i < 8; ++i) { int c = t * 8 + i; v[i] = (c < nb) ? bhist[c] : 0; s += v[i]; }
    int lane = t & 63, wid = t >> 6;
    int incl = s;
    for (int d = 1; d < 64; d <<= 1) { int u = __shfl_up(incl, (unsigned)d, 64); if (lane >= d) incl += u; }
    __shared__ int ws[4];
    if (lane == 63) ws[wid] = incl;
    __syncthreads();
    int add = 0;
    for (int w = 0; w < wid; ++w) add += ws[w];
    incl += add;
    int excl = incl - s;
    #pragma unroll
    for (int i = 0; i < 8; ++i) {
        int c = t * 8 + i;
        if (c < nb) { boffs[c] = excl; gcur[c] = excl; }
        excl += v[i];
    }
    if (t == 0) boffs[nb] = ws[0] + ws[1] + ws[2] + ws[3];
}

// ---- Pass C: batch-sorted scatter of packed keys into bucket regions
__global__ __launch_bounds__(256) void scatterC_kernel(const int* __restrict__ ei,
                                                       int* __restrict__ gcur,
                                                       int* __restrict__ keys, int nE, int nb) {
    __shared__ unsigned short sidx[BATCH];   // 32 KB
    __shared__ int hist[NB_PAD];
    __shared__ int lstart[NB_PAD];
    __shared__ int cursor[NB_PAD];
    __shared__ int gbase[NB_PAD];
    __shared__ int ws2[4];
    int tid = threadIdx.x;
    int base = blockIdx.x * BATCH;
    int cnt = nE - base; if (cnt > BATCH) cnt = BATCH;
    for (int t = tid; t < nb; t += 256) hist[t] = 0;
    __syncthreads();
    for (int t = tid; t < cnt; t += 256)
        atomicAdd(&hist[ei[nE + base + t] >> 6], 1);
    __syncthreads();
    {
        int v[8], s = 0;
        #pragma unroll
        for (int i = 0; i < 8; ++i) { int c = tid * 8 + i; v[i] = (c < nb) ? hist[c] : 0; s += v[i]; }
        int lane = tid & 63, wid = tid >> 6;
        int incl = s;
        for (int d = 1; d < 64; d <<= 1) { int u = __shfl_up(incl, (unsigned)d, 64); if (lane >= d) incl += u; }
        if (lane == 63) ws2[wid] = incl;
        __syncthreads();
        int add = 0;
        for (int w = 0; w < wid; ++w) add += ws2[w];
        incl += add;
        int excl = incl - s;
        #pragma unroll
        for (int i = 0; i < 8; ++i) {
            int c = tid * 8 + i;
            if (c < nb) { lstart[c] = excl; cursor[c] = excl; }
            excl += v[i];
        }
    }
    __syncthreads();
    for (int t = tid; t < nb; t += 256) {
        int c = hist[t];
        gbase[t] = c ? atomicAdd(&gcur[t], c) : 0;
    }
    for (int t = tid; t < cnt; t += 256) {
        int b = ei[nE + base + t] >> 6;
        int pos = atomicAdd(&cursor[b], 1);
        sidx[pos] = (unsigned short)t;
    }
    __syncthreads();
    for (int j = tid; j < cnt; j += 256) {
        int e = sidx[j];
        int d = ei[nE + base + e];
        int srcv = ei[base + e];
        int b = d >> 6;
        keys[gbase[b] + (j - lstart[b])] = srcv | ((d & 63) << 17);
    }
}

// ---- Pass C2: per-node degree (from grouped keys) -> dis
__global__ __launch_bounds__(256) void disC2_kernel(const int* __restrict__ keys,
                                                    const int* __restrict__ boffs,
                                                    float* __restrict__ dis, int n) {
    __shared__ int cnt[NPB];
    int tid = threadIdx.x, b = blockIdx.x;
    if (tid < NPB) cnt[tid] = 1;  // self-loop
    __syncthreads();
    int off = boffs[b], end = boffs[b + 1];
    for (int t = off + tid; t < end; t += 256)
        atomicAdd(&cnt[keys[t] >> 17], 1);
    __syncthreads();
    int node = b * NPB + tid;
    if (tid < NPB && node < n) dis[node] = rsqrtf((float)cnt[tid]);
}

// ---- hw1h = fp16[(x @ w1) * dis]  [N,256]x[256,32] -> [N,32] (64B rows)
__global__ __launch_bounds__(256) void hw1s_kernel(const float* __restrict__ x,
                                                   const float* __restrict__ w1,
                                                   const float* __restrict__ dis,
                                                   __half* __restrict__ hw1h, int n) {
    __shared__ float w1s[256 * 32];   // 32 KB
    __shared__ float xs[32 * 256];    // 32 KB
    int tid = threadIdx.x;
    for (int t = tid * 4; t < 8192; t += 1024)
        *(float4*)&w1s[t] = *(const float4*)&w1[t];
    int row0 = blockIdx.x * 32;
    for (int t = tid; t < 2048; t += 256) {
        int r = t >> 6, c = (t & 63) * 4;
        int row = row0 + r;
        if (row < n) *(float4*)&xs[r * 256 + c] = *(const float4*)&x[(size_t)row * 256 + c];
        else *(float4*)&xs[r * 256 + c] = make_float4(0.f, 0.f, 0.f, 0.f);
    }
    __syncthreads();
    int k = tid & 31, rg = tid >> 5;
    float a0 = 0.f, a1 = 0.f, a2 = 0.f, a3 = 0.f;
    #pragma unroll 4
    for (int c = 0; c < 256; c += 4) {
        float4 x0 = *(float4*)&xs[(rg * 4 + 0) * 256 + c];
        float4 x1 = *(float4*)&xs[(rg * 4 + 1) * 256 + c];
        float4 x2 = *(float4*)&xs[(rg * 4 + 2) * 256 + c];
        float4 x3 = *(float4*)&xs[(rg * 4 + 3) * 256 + c];
        float w0 = w1s[(c    ) * 32 + k];
        float w1v = w1s[(c + 1) * 32 + k];
        float w2v = w1s[(c + 2) * 32 + k];
        float w3 = w1s[(c + 3) * 32 + k];
        a0 += x0.x * w0 + x0.y * w1v + x0.z * w2v + x0.w * w3;
        a1 += x1.x * w0 + x1.y * w1v + x1.z * w2v + x1.w * w3;
        a2 += x2.x * w0 + x2.y * w1v + x2.z * w2v + x2.w * w3;
        a3 += x3.x * w0 + x3.y * w1v + x3.z * w2v + x3.w * w3;
    }
    int r0 = row0 + rg * 4;
    if (r0 + 0 < n) hw1h[(size_t)(r0 + 0) * 32 + k] = __float2half(a0 * dis[r0 + 0]);
    if (r0 + 1 < n) hw1h[(size_t)(r0 + 1) * 32 + k] = __float2half(a1 * dis[r0 + 1]);
    if (r0 + 2 < n) hw1h[(size_t)(r0 + 2) * 32 + k] = __float2half(a2 * dis[r0 + 2]);
    if (r0 + 3 < n) hw1h[(size_t)(r0 + 3) * 32 + k] = __float2half(a3 * dis[r0 + 3]);
}

// ---- Pass D: layer-1 aggregate via async global_load_lds staging.
// Per wave: batches of 64 edges; 4 lanes/edge x 16B; double-buffered 4KB stages.
__global__ __launch_bounds__(256) void agg1_kernel(const __half* __restrict__ hw1h,
                                                   const float* __restrict__ dis,
                                                   const int* __restrict__ keys,
                                                   const int* __restrict__ boffs,
                                                   const float* __restrict__ b1,
                                                   const float* __restrict__ w2,
                                                   float* __restrict__ hw2s, int n) {
    __shared__ float acc[NPB * 33];                  // 8.45 KB, stride 33
    __shared__ float w2s[512];
    __shared__ float b1s[32];
    __shared__ __align__(16) char stage[4][2][4096]; // 32 KB: wave x dbuf x 64 rows
    int tid = threadIdx.x, b = blockIdx.x;
    for (int t = tid; t < NPB * 33; t += 256) acc[t] = 0.f;
    for (int t = tid; t < 512; t += 256) w2s[t] = w2[t];
    if (tid < 32) b1s[tid] = b1[tid];
    __syncthreads();

    int off = boffs[b], end = boffs[b + 1];
    int lane = tid & 63, w = tid >> 6;
    int eq = lane >> 2, q = lane & 3;     // issue map: edge eq (0..15), quad q
    int ce = lane >> 1, half = lane & 1;  // consume map
    int nbatch = (end - off + 63) >> 6;
    int T = (nbatch > w) ? ((nbatch - 1 - w) >> 2) + 1 : 0;

    const char* hw1b = (const char*)hw1h;

#define LOADKEYS(j, K0, K1, K2, K3, CNT) {                                  \
        int ebase_ = off + (j) * 64;                                        \
        CNT = end - ebase_; if (CNT > 64) CNT = 64;                         \
        int cm_ = CNT - 1;                                                  \
        K0 = keys[ebase_ + (eq      < cm_ ? eq      : cm_)];                \
        K1 = keys[ebase_ + (16 + eq < cm_ ? 16 + eq : cm_)];                \
        K2 = keys[ebase_ + (32 + eq < cm_ ? 32 + eq : cm_)];                \
        K3 = keys[ebase_ + (48 + eq < cm_ ? 48 + eq : cm_)];                \
    }

#define ISSUE(ST, K0, K1, K2, K3) {                                        \
        gload16(hw1b + (size_t)((K0) & 0x1FFFF) * 64 + q * 16, (ST));       \
        gload16(hw1b + (size_t)((K1) & 0x1FFFF) * 64 + q * 16, (ST) + 1024);\
        gload16(hw1b + (size_t)((K2) & 0x1FFFF) * 64 + q * 16, (ST) + 2048);\
        gload16(hw1b + (size_t)((K3) & 0x1FFFF) * 64 + q * 16, (ST) + 3072);\
    }

#define CONSUME(ST, KC0, KC1, KC2, KC3, CNT) {                              \
        int srcl_ = (ce & 15) << 2;                                         \
        int v0_ = __shfl(KC0, srcl_, 64);                                   \
        int v1_ = __shfl(KC1, srcl_, 64);                                   \
        int v2_ = __shfl(KC2, srcl_, 64);                                   \
        int v3_ = __shfl(KC3, srcl_, 64);                                   \
        _Pragma("unroll")                                                   \
        for (int p_ = 0; p_ < 2; ++p_) {                                    \
            int e_ = ce + p_ * 32;                                          \
            int kk_ = p_ ? ((e_ & 16) ? v3_ : v2_) : ((e_ & 16) ? v1_ : v0_);\
            if (e_ < CNT) {                                                 \
                const char* sp_ = (ST) + ((e_ >> 4) << 10) + ((e_ & 15) << 6) + (half << 5); \
                int4 ra_ = *(const int4*)sp_;                               \
                int4 rb_ = *(const int4*)(sp_ + 16);                        \
                float* ap_ = &acc[(kk_ >> 17) * 33 + (half << 4)];          \
                union { int4 i4; __half2 h2[4]; } ua_, ub_;                 \
                ua_.i4 = ra_; ub_.i4 = rb_;                                 \
                _Pragma("unroll")                                           \
                for (int u_ = 0; u_ < 4; ++u_) {                            \
                    float2 f_ = __half22float2(ua_.h2[u_]);                 \
                    atomicAdd(ap_ + u_ * 2, f_.x);                          \
                    atomicAdd(ap_ + u_ * 2 + 1, f_.y);                      \
                }                                                           \
                _Pragma("unroll")                                           \
                for (int u_ = 0; u_ < 4; ++u_) {                            \
                    float2 f_ = __half22float2(ub_.h2[u_]);                 \
                    atomicAdd(ap_ + 8 + u_ * 2, f_.x);                      \
                    atomicAdd(ap_ + 8 + u_ * 2 + 1, f_.y);                  \
                }                                                           \
            }                                                               \
        }                                                                   \
    }

    if (T > 0) {
        char* st0 = (char*)&stage[w][0][0];
        char* st1 = (char*)&stage[w][1][0];
        int kIss0, kIss1, kIss2, kIss3, cntIss;
        int kPre0 = 0, kPre1 = 0, kPre2 = 0, kPre3 = 0, cntPre = 0;
        int kCon0, kCon1, kCon2, kCon3, cntCon;
        LOADKEYS(w, kIss0, kIss1, kIss2, kIss3, cntIss);
        if (T > 1) LOADKEYS(w + 4, kPre0, kPre1, kPre2, kPre3, cntPre);
        ISSUE(st0, kIss0, kIss1, kIss2, kIss3);
        kCon0 = kIss0; kCon1 = kIss1; kCon2 = kIss2; kCon3 = kIss3; cntCon = cntIss;
        kIss0 = kPre0; kIss1 = kPre1; kIss2 = kPre2; kIss3 = kPre3; cntIss = cntPre;
        for (int t = 1; t < T; ++t) {
            char* stc = (t & 1) ? st1 : st0;   // issue target
            char* stp = (t & 1) ? st0 : st1;   // consume source
            if (t + 1 < T) {
                LOADKEYS(w + 4 * (t + 1), kPre0, kPre1, kPre2, kPre3, cntPre);
                ISSUE(stc, kIss0, kIss1, kIss2, kIss3);
                asm volatile("s_waitcnt vmcnt(8)" ::: "memory");
                __builtin_amdgcn_sched_barrier(0);
            } else {
                ISSUE(stc, kIss0, kIss1, kIss2, kIss3);
                asm volatile("s_waitcnt vmcnt(4)" ::: "memory");
                __builtin_amdgcn_sched_barrier(0);
            }
            CONSUME(stp, kCon0, kCon1, kCon2, kCon3, cntCon);
            kCon0 = kIss0; kCon1 = kIss1; kCon2 = kIss2; kCon3 = kIss3; cntCon = cntIss;
            kIss0 = kPre0; kIss1 = kPre1; kIss2 = kPre2; kIss3 = kPre3; cntIss = cntPre;
        }
        asm volatile("s_waitcnt vmcnt(0)" ::: "memory");
        __builtin_amdgcn_sched_barrier(0);
        char* stl = ((T - 1) & 1) ? st1 : st0;
        CONSUME(stl, kCon0, kCon1, kCon2, kCon3, cntCon);
    }
#undef LOADKEYS
#undef ISSUE
#undef CONSUME

    __syncthreads();
    int node0 = b * NPB;
    for (int t = tid; t < NPB * 32; t += 256) {
        int ld = t >> 5, kk = t & 31;
        int node = node0 + ld;
        if (node < n) {
            float dn = dis[node];
            float self = __half2float(hw1h[(size_t)node * 32 + kk]);
            float h1 = dn * (acc[ld * 33 + kk] + self) + b1s[kk];
            acc[ld * 33 + kk] = fmaxf(h1, 0.f);
        }
    }
    __syncthreads();
    for (int t = tid; t < NPB * 16; t += 256) {
        int ld = t >> 4, kk = t & 15;
        int node = node0 + ld;
        if (node < n) {
            float a = 0.f;
            #pragma unroll
            for (int cc = 0; cc < 32; ++cc) a += acc[ld * 33 + cc] * w2s[cc * 16 + kk];
            hw2s[(size_t)node * 16 + kk] = a * dis[node];
        }
    }
}

// ---- Pass E: layer-2 aggregate, selected-dst only (per-lane keys, ~4% hit)
__global__ __launch_bounds__(256) void agg2_kernel(const float* __restrict__ hw2s,
                                                   const float* __restrict__ dis,
                                                   const int* __restrict__ keys,
                                                   const int* __restrict__ boffs,
                                                   const int* __restrict__ needed,
                                                   const float* __restrict__ b2,
                                                   float* __restrict__ h2, int n) {
    __shared__ float acc[NPB * 17];   // stride 17
    __shared__ int fl[NPB];
    int tid = threadIdx.x, b = blockIdx.x;
    int node0 = b * NPB;
    if (tid < NPB) { int node = node0 + tid; fl[tid] = (node < n) ? needed[node] : 0; }
    for (int t = tid; t < NPB * 17; t += 256) acc[t] = 0.f;
    __syncthreads();
    int off = boffs[b], end = boffs[b + 1];
    int base = off + tid;
    int kk = (base < end) ? keys[base] : 0;
    while (base < end) {
        int nbase = base + 256;
        int kn = (nbase < end) ? keys[nbase] : 0;
        int ld = kk >> 17;
        if (fl[ld]) {
            const float4* src = (const float4*)&hw2s[(size_t)(kk & 0x1FFFF) * 16];
            float4 v0 = src[0], v1 = src[1], v2 = src[2], v3 = src[3];
            float* ap = &acc[ld * 17];
            atomicAdd(ap + 0, v0.x);  atomicAdd(ap + 1, v0.y);
            atomicAdd(ap + 2, v0.z);  atomicAdd(ap + 3, v0.w);
            atomicAdd(ap + 4, v1.x);  atomicAdd(ap + 5, v1.y);
            atomicAdd(ap + 6, v1.z);  atomicAdd(ap + 7, v1.w);
            atomicAdd(ap + 8, v2.x);  atomicAdd(ap + 9, v2.y);
            atomicAdd(ap + 10, v2.z); atomicAdd(ap + 11, v2.w);
            atomicAdd(ap + 12, v3.x); atomicAdd(ap + 13, v3.y);
            atomicAdd(ap + 14, v3.z); atomicAdd(ap + 15, v3.w);
        }
        kk = kn; base = nbase;
    }
    __syncthreads();
    for (int t = tid; t < NPB * 16; t += 256) {
        int ld = t >> 4, kk2 = t & 15;
        int node = node0 + ld;
        if (node < n && fl[ld]) {
            float dn = dis[node];
            h2[node * 16 + kk2] = dn * (acc[ld * 17 + kk2] + hw2s[(size_t)node * 16 + kk2]) + b2[kk2];
        }
    }
}

// ---- pairwise concat + MoE1 + MoE2 + log_softmax
__global__ __launch_bounds__(256) void pair_moe_kernel(const float* __restrict__ h2,
                                                       const int* __restrict__ nodes,
                                                       const float* __restrict__ gate1_w,
                                                       const float* __restrict__ e1_w,
                                                       const float* __restrict__ e1_b,
                                                       const float* __restrict__ gate2_w,
                                                       const float* __restrict__ e2_w,
                                                       const float* __restrict__ e2_b,
                                                       float* __restrict__ out1,
                                                       float* __restrict__ out2, int M) {
    __shared__ float hjs[50 * 16];
    __shared__ float g1s[32 * 4];
    __shared__ float e1ws[4 * 32 * 16];
    __shared__ float e1bs[4 * 16];
    __shared__ float g2s[16 * 4];
    __shared__ float e2ws[4 * 16 * 2];
    __shared__ float e2bs[4 * 2];
    int tid = threadIdx.x;
    for (int t = tid; t < 800; t += 256) { int j = t >> 4, c = t & 15; hjs[t] = h2[nodes[j] * 16 + c]; }
    for (int t = tid; t < 128; t += 256) g1s[t] = gate1_w[t];
    for (int t = tid; t < 2048; t += 256) e1ws[t] = e1_w[t];
    for (int t = tid; t < 64; t += 256) e1bs[t] = e1_b[t];
    for (int t = tid; t < 64; t += 256) g2s[t] = gate2_w[t];
    for (int t = tid; t < 128; t += 256) e2ws[t] = e2_w[t];
    if (tid < 8) e2bs[tid] = e2_b[tid];
    __syncthreads();

    int m = blockIdx.x * 256 + tid;
    if (m >= M) return;
    int i = m / 50, j = m - i * 50;

    float xs[32];
    int ni = nodes[i];
    float4 a0 = *(const float4*)&h2[ni * 16];
    float4 a1 = *(const float4*)&h2[ni * 16 + 4];
    float4 a2 = *(const float4*)&h2[ni * 16 + 8];
    float4 a3 = *(const float4*)&h2[ni * 16 + 12];
    xs[0]=a0.x; xs[1]=a0.y; xs[2]=a0.z; xs[3]=a0.w;
    xs[4]=a1.x; xs[5]=a1.y; xs[6]=a1.z; xs[7]=a1.w;
    xs[8]=a2.x; xs[9]=a2.y; xs[10]=a2.z; xs[11]=a2.w;
    xs[12]=a3.x; xs[13]=a3.y; xs[14]=a3.z; xs[15]=a3.w;
    #pragma unroll
    for (int c = 0; c < 16; ++c) xs[16 + c] = hjs[j * 16 + c];

    #pragma unroll
    for (int c = 0; c < 32; c += 4)
        *(float4*)&out2[(size_t)m * 32 + c] = make_float4(xs[c], xs[c+1], xs[c+2], xs[c+3]);

    float g[4] = {0.f, 0.f, 0.f, 0.f};
    #pragma unroll
    for (int c = 0; c < 32; ++c) {
        float xv = xs[c];
        #pragma unroll
        for (int e = 0; e < 4; ++e) g[e] += xv * g1s[c * 4 + e];
    }
    int idx = 0; float best = g[0];
    #pragma unroll
    for (int e = 1; e < 4; ++e) if (g[e] > best) { best = g[e]; idx = e; }
    float z[16];
    #pragma unroll
    for (int o = 0; o < 16; ++o) {
        float a = e1bs[idx * 16 + o];
        #pragma unroll
        for (int c = 0; c < 32; ++c) a += xs[c] * e1ws[(idx * 32 + c) * 16 + o];
        z[o] = fmaxf(a, 0.f);
    }

    float g2[4] = {0.f, 0.f, 0.f, 0.f};
    #pragma unroll
    for (int c = 0; c < 16; ++c) {
        float zv = z[c];
        #pragma unroll
        for (int e = 0; e < 4; ++e) g2[e] += zv * g2s[c * 4 + e];
    }
    int idx2 = 0; float best2 = g2[0];
    #pragma unroll
    for (int e = 1; e < 4; ++e) if (g2[e] > best2) { best2 = g2[e]; idx2 = e; }
    float z2[2];
    #pragma unroll
    for (int o = 0; o < 2; ++o) {
        float a = e2bs[idx2 * 2 + o];
        #pragma unroll
        for (int c = 0; c < 16; ++c) a += z[c] * e2ws[(idx2 * 16 + c) * 2 + o];
        z2[o] = a;
    }

    float mx = fmaxf(z2[0], z2[1]);
    float l = logf(expf(z2[0] - mx) + expf(z2[1] - mx));
    out1[(size_t)m * 2 + 0] = z2[0] - mx - l;
    out1[(size_t)m * 2 + 1] = z2[1] - mx - l;
}

extern "C" void kernel_launch(void* const* d_in, const int* in_sizes, int n_in,
                              void* d_out, int out_size, void* d_ws, size_t ws_size,
                              hipStream_t stream) {
    const float* x       = (const float*)d_in[0];
    const float* w1      = (const float*)d_in[1];
    const float* b1      = (const float*)d_in[2];
    const float* w2      = (const float*)d_in[3];
    const float* b2      = (const float*)d_in[4];
    const float* gate1_w = (const float*)d_in[5];
    const float* e1_w    = (const float*)d_in[6];
    const float* e1_b    = (const float*)d_in[7];
    const float* gate2_w = (const float*)d_in[8];
    const float* e2_w    = (const float*)d_in[9];
    const float* e2_b    = (const float*)d_in[10];
    const int*   ei      = (const int*)d_in[11];
    const int*   nodes   = (const int*)d_in[12];

    const int n    = in_sizes[0] / 256;      // 100000
    const int nE   = in_sizes[11] / 2;       // 3200000
    const int nsel = in_sizes[12];           // 4096
    const int M    = nsel * 50;              // 204800
    const int nb   = (n + NPB - 1) / NPB;    // 1563

    size_t off = 0;
    auto alloc = [&](size_t bytes) -> void* {
        void* p = (char*)d_ws + off;
        off += (bytes + 255) & ~(size_t)255;
        return p;
    };
    float*  dis    = (float*)alloc((size_t)n * 4);
    int*    needed = (int*)alloc((size_t)n * 4);
    int*    bhist  = (int*)alloc((size_t)nb * 4);
    int*    boffs  = (int*)alloc((size_t)(nb + 1) * 4);
    int*    gcur   = (int*)alloc((size_t)nb * 4);
    int*    keys   = (int*)alloc((size_t)nE * 4);
    __half* hw1h   = (__half*)alloc((size_t)n * 32 * 2);
    float*  hw2s   = (float*)alloc((size_t)n * 16 * 4);
    float*  h2     = (float*)alloc((size_t)n * 16 * 4);
    if (off > ws_size) return;

    float* out1 = (float*)d_out;              // [M,2]
    float* out2 = out1 + (size_t)M * 2;       // [M,32]

    zero_kernel<<<(n + 255) / 256, 256, 0, stream>>>(needed, n);
    zero_kernel<<<(nb + 255) / 256, 256, 0, stream>>>(bhist, nb);
    needed_kernel<<<(nsel + 255) / 256, 256, 0, stream>>>(nodes, needed, nsel);
    histA_kernel<<<(nE + 4095) / 4096, 256, 0, stream>>>(ei, bhist, nE, nb);
    scanB_kernel<<<1, 256, 0, stream>>>(bhist, boffs, gcur, nb);
    scatterC_kernel<<<(nE + BATCH - 1) / BATCH, 256, 0, stream>>>(ei, gcur, keys, nE, nb);
    disC2_kernel<<<nb, 256, 0, stream>>>(keys, boffs, dis, n);
    hw1s_kernel<<<(n + 31) / 32, 256, 0, stream>>>(x, w1, dis, hw1h, n);
    agg1_kernel<<<nb, 256, 0, stream>>>(hw1h, dis, keys, boffs, b1, w2, hw2s, n);
    agg2_kernel<<<nb, 256, 0, stream>>>(hw2s, dis, keys, boffs, needed, b2, h2, n);
    pair_moe_kernel<<<(M + 255) / 256, 256, 0, stream>>>(h2, nodes, gate1_w, e1_w, e1_b,
                                                         gate2_w, e2_w, e2_b, out1, out2, M);
}

// Round 7
// 826.893 us; speedup vs baseline: 1.0482x; 1.0056x over previous
//
#include <hip/hip_runtime.h>
#include <hip/hip_fp16.h>
#include <math.h>

// ---------------------------------------------------------------------------
// GCNSim: 2-layer GCN via dst-bucketed edge keys + register-gather aggregation.
// key = src (17b) | local_dst (6b) << 17 ; NPB = 64 nodes per bucket.
// hw1h = fp16[(x@w1)*dis] as [N][32] (64B rows); per-edge gather is one line.
// agg1: 4 inline-asm global_load_dwordx4 per lane per iter -> 64 lines in
// flight per wave (compiler cannot serialize distinct asm outputs).
// ---------------------------------------------------------------------------

#define NPB 64
#define NB_PAD 2048
#define BATCH 16384

typedef int v4i __attribute__((ext_vector_type(4)));

__global__ void zero_kernel(int* __restrict__ p, int c) {
    int i = blockIdx.x * 256 + threadIdx.x;
    if (i < c) p[i] = 0;
}

__global__ void needed_kernel(const int* __restrict__ nodes, int* __restrict__ needed, int nsel) {
    int i = blockIdx.x * 256 + threadIdx.x;
    if (i < nsel) needed[nodes[i]] = 1;
}

// ---- Pass A: per-bucket edge histogram (LDS-aggregated)
__global__ __launch_bounds__(256) void histA_kernel(const int* __restrict__ ei,
                                                    int* __restrict__ bhist, int nE, int nb) {
    __shared__ int h[NB_PAD];
    int tid = threadIdx.x;
    for (int t = tid; t < nb; t += 256) h[t] = 0;
    __syncthreads();
    int base = blockIdx.x * 4096;
    for (int t = tid; t < 4096; t += 256) {
        int e = base + t;
        if (e < nE) atomicAdd(&h[ei[nE + e] >> 6], 1);
    }
    __syncthreads();
    for (int t = tid; t < nb; t += 256) { int c = h[t]; if (c) atomicAdd(&bhist[t], c); }
}

// ---- Pass B: exclusive scan of bucket counts -> boffs[nb+1], gcur copy
__global__ __launch_bounds__(256) void scanB_kernel(const int* __restrict__ bhist,
                                                    int* __restrict__ boffs,
                                                    int* __restrict__ gcur, int nb) {
    int t = threadIdx.x;
    int v[8], s = 0;
    #pragma unroll
    for (int i = 0; i < 8; ++i) { int c = t * 8 + i; v[i] = (c < nb) ? bhist[c] : 0; s += v[i]; }
    int lane = t & 63, wid = t >> 6;
    int incl = s;
    for (int d = 1; d < 64; d <<= 1) { int u = __shfl_up(incl, (unsigned)d, 64); if (lane >= d) incl += u; }
    __shared__ int ws[4];
    if (lane == 63) ws[wid] = incl;
    __syncthreads();
    int add = 0;
    for (int w = 0; w < wid; ++w) add += ws[w];
    incl += add;
    int excl = incl - s;
    #pragma unroll
    for (int i = 0; i < 8; ++i) {
        int c = t * 8 + i;
        if (c < nb) { boffs[c] = excl; gcur[c] = excl; }
        excl += v[i];
    }
    if (t == 0) boffs[nb] = ws[0] + ws[1] + ws[2] + ws[3];
}

// ---- Pass C: batch-sorted scatter of packed keys into bucket regions
__global__ __launch_bounds__(256) void scatterC_kernel(const int* __restrict__ ei,
                                                       int* __restrict__ gcur,
                                                       int* __restrict__ keys, int nE, int nb) {
    __shared__ unsigned short sidx[BATCH];   // 32 KB
    __shared__ int hist[NB_PAD];
    __shared__ int lstart[NB_PAD];
    __shared__ int cursor[NB_PAD];
    __shared__ int gbase[NB_PAD];
    __shared__ int ws2[4];
    int tid = threadIdx.x;
    int base = blockIdx.x * BATCH;
    int cnt = nE - base; if (cnt > BATCH) cnt = BATCH;
    for (int t = tid; t < nb; t += 256) hist[t] = 0;
    __syncthreads();
    for (int t = tid; t < cnt; t += 256)
        atomicAdd(&hist[ei[nE + base + t] >> 6], 1);
    __syncthreads();
    {
        int v[8], s = 0;
        #pragma unroll
        for (int i = 0; i < 8; ++i) { int c = tid * 8 + i; v[i] = (c < nb) ? hist[c] : 0; s += v[i]; }
        int lane = tid & 63, wid = tid >> 6;
        int incl = s;
        for (int d = 1; d < 64; d <<= 1) { int u = __shfl_up(incl, (unsigned)d, 64); if (lane >= d) incl += u; }
        if (lane == 63) ws2[wid] = incl;
        __syncthreads();
        int add = 0;
        for (int w = 0; w < wid; ++w) add += ws2[w];
        incl += add;
        int excl = incl - s;
        #pragma unroll
        for (int i = 0; i < 8; ++i) {
            int c = tid * 8 + i;
            if (c < nb) { lstart[c] = excl; cursor[c] = excl; }
            excl += v[i];
        }
    }
    __syncthreads();
    for (int t = tid; t < nb; t += 256) {
        int c = hist[t];
        gbase[t] = c ? atomicAdd(&gcur[t], c) : 0;
    }
    for (int t = tid; t < cnt; t += 256) {
        int b = ei[nE + base + t] >> 6;
        int pos = atomicAdd(&cursor[b], 1);
        sidx[pos] = (unsigned short)t;
    }
    __syncthreads();
    for (int j = tid; j < cnt; j += 256) {
        int e = sidx[j];
        int d = ei[nE + base + e];
        int srcv = ei[base + e];
        int b = d >> 6;
        keys[gbase[b] + (j - lstart[b])] = srcv | ((d & 63) << 17);
    }
}

// ---- Pass C2: per-node degree (from grouped keys) -> dis
__global__ __launch_bounds__(256) void disC2_kernel(const int* __restrict__ keys,
                                                    const int* __restrict__ boffs,
                                                    float* __restrict__ dis, int n) {
    __shared__ int cnt[NPB];
    int tid = threadIdx.x, b = blockIdx.x;
    if (tid < NPB) cnt[tid] = 1;  // self-loop
    __syncthreads();
    int off = boffs[b], end = boffs[b + 1];
    for (int t = off + tid; t < end; t += 256)
        atomicAdd(&cnt[keys[t] >> 17], 1);
    __syncthreads();
    int node = b * NPB + tid;
    if (tid < NPB && node < n) dis[node] = rsqrtf((float)cnt[tid]);
}

// ---- hw1h = fp16[(x @ w1) * dis]  [N,256]x[256,32] -> [N,32] (64B rows)
__global__ __launch_bounds__(256) void hw1s_kernel(const float* __restrict__ x,
                                                   const float* __restrict__ w1,
                                                   const float* __restrict__ dis,
                                                   __half* __restrict__ hw1h, int n) {
    __shared__ float w1s[256 * 32];   // 32 KB
    __shared__ float xs[32 * 256];    // 32 KB
    int tid = threadIdx.x;
    for (int t = tid * 4; t < 8192; t += 1024)
        *(float4*)&w1s[t] = *(const float4*)&w1[t];
    int row0 = blockIdx.x * 32;
    for (int t = tid; t < 2048; t += 256) {
        int r = t >> 6, c = (t & 63) * 4;
        int row = row0 + r;
        if (row < n) *(float4*)&xs[r * 256 + c] = *(const float4*)&x[(size_t)row * 256 + c];
        else *(float4*)&xs[r * 256 + c] = make_float4(0.f, 0.f, 0.f, 0.f);
    }
    __syncthreads();
    int k = tid & 31, rg = tid >> 5;
    float a0 = 0.f, a1 = 0.f, a2 = 0.f, a3 = 0.f;
    #pragma unroll 4
    for (int c = 0; c < 256; c += 4) {
        float4 x0 = *(float4*)&xs[(rg * 4 + 0) * 256 + c];
        float4 x1 = *(float4*)&xs[(rg * 4 + 1) * 256 + c];
        float4 x2 = *(float4*)&xs[(rg * 4 + 2) * 256 + c];
        float4 x3 = *(float4*)&xs[(rg * 4 + 3) * 256 + c];
        float w0 = w1s[(c    ) * 32 + k];
        float w1v = w1s[(c + 1) * 32 + k];
        float w2v = w1s[(c + 2) * 32 + k];
        float w3 = w1s[(c + 3) * 32 + k];
        a0 += x0.x * w0 + x0.y * w1v + x0.z * w2v + x0.w * w3;
        a1 += x1.x * w0 + x1.y * w1v + x1.z * w2v + x1.w * w3;
        a2 += x2.x * w0 + x2.y * w1v + x2.z * w2v + x2.w * w3;
        a3 += x3.x * w0 + x3.y * w1v + x3.z * w2v + x3.w * w3;
    }
    int r0 = row0 + rg * 4;
    if (r0 + 0 < n) hw1h[(size_t)(r0 + 0) * 32 + k] = __float2half(a0 * dis[r0 + 0]);
    if (r0 + 1 < n) hw1h[(size_t)(r0 + 1) * 32 + k] = __float2half(a1 * dis[r0 + 1]);
    if (r0 + 2 < n) hw1h[(size_t)(r0 + 2) * 32 + k] = __float2half(a2 * dis[r0 + 2]);
    if (r0 + 3 < n) hw1h[(size_t)(r0 + 3) * 32 + k] = __float2half(a3 * dis[r0 + 3]);
}

// ---- Pass D: layer-1 aggregate. Per iter per wave: 16 edges x 4 batches via
// 4 independent inline-asm dwordx4 gathers (64 lines in flight), one vmcnt(0),
// then cvt + LDS atomics. Epilogue: ReLU + @w2 -> hw2s.
__global__ __launch_bounds__(256) void agg1_kernel(const __half* __restrict__ hw1h,
                                                   const float* __restrict__ dis,
                                                   const int* __restrict__ keys,
                                                   const int* __restrict__ boffs,
                                                   const float* __restrict__ b1,
                                                   const float* __restrict__ w2,
                                                   float* __restrict__ hw2s, int n) {
    __shared__ float acc[NPB * 33];   // 8.45 KB, stride 33
    __shared__ float w2s[512];
    __shared__ float b1s[32];
    int tid = threadIdx.x, b = blockIdx.x;
    for (int t = tid; t < NPB * 33; t += 256) acc[t] = 0.f;
    for (int t = tid; t < 512; t += 256) w2s[t] = w2[t];
    if (tid < 32) b1s[tid] = b1[tid];
    __syncthreads();

    int off = boffs[b], end = boffs[b + 1];
    int lane = tid & 63, w = tid >> 6;
    int es = lane >> 2, q = lane & 3;   // edge slot 0..15, quad 0..3 (16B each)

#define CONS(D, K, E) if ((E) < cnt) {                                     \
        float* ap = &acc[((K) >> 17) * 33 + q * 8];                        \
        union { v4i i4; __half2 h[4]; } u_; u_.i4 = (D);                   \
        _Pragma("unroll")                                                  \
        for (int j_ = 0; j_ < 4; ++j_) {                                   \
            float2 f_ = __half22float2(u_.h[j_]);                          \
            atomicAdd(ap + j_ * 2, f_.x);                                  \
            atomicAdd(ap + j_ * 2 + 1, f_.y);                              \
        } }

    for (int base = off + w * 64; base < end; base += 256) {
        int cnt = end - base; if (cnt > 64) cnt = 64;
        int cm = cnt - 1;
        int e0 = es, e1 = 16 + es, e2 = 32 + es, e3 = 48 + es;
        int k0 = keys[base + (e0 < cnt ? e0 : cm)];
        int k1 = keys[base + (e1 < cnt ? e1 : cm)];
        int k2 = keys[base + (e2 < cnt ? e2 : cm)];
        int k3 = keys[base + (e3 < cnt ? e3 : cm)];
        const __half* p0 = hw1h + (size_t)(k0 & 0x1FFFF) * 32 + q * 8;
        const __half* p1 = hw1h + (size_t)(k1 & 0x1FFFF) * 32 + q * 8;
        const __half* p2 = hw1h + (size_t)(k2 & 0x1FFFF) * 32 + q * 8;
        const __half* p3 = hw1h + (size_t)(k3 & 0x1FFFF) * 32 + q * 8;
        v4i d0, d1, d2, d3;
        asm volatile("global_load_dwordx4 %0, %1, off" : "=&v"(d0) : "v"(p0) : "memory");
        asm volatile("global_load_dwordx4 %0, %1, off" : "=&v"(d1) : "v"(p1) : "memory");
        asm volatile("global_load_dwordx4 %0, %1, off" : "=&v"(d2) : "v"(p2) : "memory");
        asm volatile("global_load_dwordx4 %0, %1, off" : "=&v"(d3) : "v"(p3) : "memory");
        asm volatile("s_waitcnt vmcnt(0)" ::: "memory");
        __builtin_amdgcn_sched_barrier(0);
        CONS(d0, k0, e0)
        CONS(d1, k1, e1)
        CONS(d2, k2, e2)
        CONS(d3, k3, e3)
    }
#undef CONS

    __syncthreads();
    int node0 = b * NPB;
    for (int t = tid; t < NPB * 32; t += 256) {
        int ld = t >> 5, kk = t & 31;
        int node = node0 + ld;
        if (node < n) {
            float dn = dis[node];
            float self = __half2float(hw1h[(size_t)node * 32 + kk]);
            float h1 = dn * (acc[ld * 33 + kk] + self) + b1s[kk];
            acc[ld * 33 + kk] = fmaxf(h1, 0.f);
        }
    }
    __syncthreads();
    for (int t = tid; t < NPB * 16; t += 256) {
        int ld = t >> 4, kk = t & 15;
        int node = node0 + ld;
        if (node < n) {
            float a = 0.f;
            #pragma unroll
            for (int cc = 0; cc < 32; ++cc) a += acc[ld * 33 + cc] * w2s[cc * 16 + kk];
            hw2s[(size_t)node * 16 + kk] = a * dis[node];
        }
    }
}

// ---- Pass E: layer-2 aggregate, selected-dst only (per-lane keys, ~4% hit)
__global__ __launch_bounds__(256) void agg2_kernel(const float* __restrict__ hw2s,
                                                   const float* __restrict__ dis,
                                                   const int* __restrict__ keys,
                                                   const int* __restrict__ boffs,
                                                   const int* __restrict__ needed,
                                                   const float* __restrict__ b2,
                                                   float* __restrict__ h2, int n) {
    __shared__ float acc[NPB * 17];   // stride 17
    __shared__ int fl[NPB];
    int tid = threadIdx.x, b = blockIdx.x;
    int node0 = b * NPB;
    if (tid < NPB) { int node = node0 + tid; fl[tid] = (node < n) ? needed[node] : 0; }
    for (int t = tid; t < NPB * 17; t += 256) acc[t] = 0.f;
    __syncthreads();
    int off = boffs[b], end = boffs[b + 1];
    int base = off + tid;
    int kk = (base < end) ? keys[base] : 0;
    while (base < end) {
        int nbase = base + 256;
        int kn = (nbase < end) ? keys[nbase] : 0;
        int ld = kk >> 17;
        if (fl[ld]) {
            const float4* src = (const float4*)&hw2s[(size_t)(kk & 0x1FFFF) * 16];
            float4 v0 = src[0], v1 = src[1], v2 = src[2], v3 = src[3];
            float* ap = &acc[ld * 17];
            atomicAdd(ap + 0, v0.x);  atomicAdd(ap + 1, v0.y);
            atomicAdd(ap + 2, v0.z);  atomicAdd(ap + 3, v0.w);
            atomicAdd(ap + 4, v1.x);  atomicAdd(ap + 5, v1.y);
            atomicAdd(ap + 6, v1.z);  atomicAdd(ap + 7, v1.w);
            atomicAdd(ap + 8, v2.x);  atomicAdd(ap + 9, v2.y);
            atomicAdd(ap + 10, v2.z); atomicAdd(ap + 11, v2.w);
            atomicAdd(ap + 12, v3.x); atomicAdd(ap + 13, v3.y);
            atomicAdd(ap + 14, v3.z); atomicAdd(ap + 15, v3.w);
        }
        kk = kn; base = nbase;
    }
    __syncthreads();
    for (int t = tid; t < NPB * 16; t += 256) {
        int ld = t >> 4, kk2 = t & 15;
        int node = node0 + ld;
        if (node < n && fl[ld]) {
            float dn = dis[node];
            h2[node * 16 + kk2] = dn * (acc[ld * 17 + kk2] + hw2s[(size_t)node * 16 + kk2]) + b2[kk2];
        }
    }
}

// ---- pairwise concat + MoE1 + MoE2 + log_softmax
__global__ __launch_bounds__(256) void pair_moe_kernel(const float* __restrict__ h2,
                                                       const int* __restrict__ nodes,
                                                       const float* __restrict__ gate1_w,
                                                       const float* __restrict__ e1_w,
                                                       const float* __restrict__ e1_b,
                                                       const float* __restrict__ gate2_w,
                                                       const float* __restrict__ e2_w,
                                                       const float* __restrict__ e2_b,
                                                       float* __restrict__ out1,
                                                       float* __restrict__ out2, int M) {
    __shared__ float hjs[50 * 16];
    __shared__ float g1s[32 * 4];
    __shared__ float e1ws[4 * 32 * 16];
    __shared__ float e1bs[4 * 16];
    __shared__ float g2s[16 * 4];
    __shared__ float e2ws[4 * 16 * 2];
    __shared__ float e2bs[4 * 2];
    int tid = threadIdx.x;
    for (int t = tid; t < 800; t += 256) { int j = t >> 4, c = t & 15; hjs[t] = h2[nodes[j] * 16 + c]; }
    for (int t = tid; t < 128; t += 256) g1s[t] = gate1_w[t];
    for (int t = tid; t < 2048; t += 256) e1ws[t] = e1_w[t];
    for (int t = tid; t < 64; t += 256) e1bs[t] = e1_b[t];
    for (int t = tid; t < 64; t += 256) g2s[t] = gate2_w[t];
    for (int t = tid; t < 128; t += 256) e2ws[t] = e2_w[t];
    if (tid < 8) e2bs[tid] = e2_b[tid];
    __syncthreads();

    int m = blockIdx.x * 256 + tid;
    if (m >= M) return;
    int i = m / 50, j = m - i * 50;

    float xs[32];
    int ni = nodes[i];
    float4 a0 = *(const float4*)&h2[ni * 16];
    float4 a1 = *(const float4*)&h2[ni * 16 + 4];
    float4 a2 = *(const float4*)&h2[ni * 16 + 8];
    float4 a3 = *(const float4*)&h2[ni * 16 + 12];
    xs[0]=a0.x; xs[1]=a0.y; xs[2]=a0.z; xs[3]=a0.w;
    xs[4]=a1.x; xs[5]=a1.y; xs[6]=a1.z; xs[7]=a1.w;
    xs[8]=a2.x; xs[9]=a2.y; xs[10]=a2.z; xs[11]=a2.w;
    xs[12]=a3.x; xs[13]=a3.y; xs[14]=a3.z; xs[15]=a3.w;
    #pragma unroll
    for (int c = 0; c < 16; ++c) xs[16 + c] = hjs[j * 16 + c];

    #pragma unroll
    for (int c = 0; c < 32; c += 4)
        *(float4*)&out2[(size_t)m * 32 + c] = make_float4(xs[c], xs[c+1], xs[c+2], xs[c+3]);

    float g[4] = {0.f, 0.f, 0.f, 0.f};
    #pragma unroll
    for (int c = 0; c < 32; ++c) {
        float xv = xs[c];
        #pragma unroll
        for (int e = 0; e < 4; ++e) g[e] += xv * g1s[c * 4 + e];
    }
    int idx = 0; float best = g[0];
    #pragma unroll
    for (int e = 1; e < 4; ++e) if (g[e] > best) { best = g[e]; idx = e; }
    float z[16];
    #pragma unroll
    for (int o = 0; o < 16; ++o) {
        float a = e1bs[idx * 16 + o];
        #pragma unroll
        for (int c = 0; c < 32; ++c) a += xs[c] * e1ws[(idx * 32 + c) * 16 + o];
        z[o] = fmaxf(a, 0.f);
    }

    float g2[4] = {0.f, 0.f, 0.f, 0.f};
    #pragma unroll
    for (int c = 0; c < 16; ++c) {
        float zv = z[c];
        #pragma unroll
        for (int e = 0; e < 4; ++e) g2[e] += zv * g2s[c * 4 + e];
    }
    int idx2 = 0; float best2 = g2[0];
    #pragma unroll
    for (int e = 1; e < 4; ++e) if (g2[e] > best2) { best2 = g2[e]; idx2 = e; }
    float z2[2];
    #pragma unroll
    for (int o = 0; o < 2; ++o) {
        float a = e2bs[idx2 * 2 + o];
        #pragma unroll
        for (int c = 0; c < 16; ++c) a += z[c] * e2ws[(idx2 * 16 + c) * 2 + o];
        z2[o] = a;
    }

    float mx = fmaxf(z2[0], z2[1]);
    float l = logf(expf(z2[0] - mx) + expf(z2[1] - mx));
    out1[(size_t)m * 2 + 0] = z2[0] - mx - l;
    out1[(size_t)m * 2 + 1] = z2[1] - mx - l;
}

extern "C" void kernel_launch(void* const* d_in, const int* in_sizes, int n_in,
                              void* d_out, int out_size, void* d_ws, size_t ws_size,
                              hipStream_t stream) {
    const float* x       = (const float*)d_in[0];
    const float* w1      = (const float*)d_in[1];
    const float* b1      = (const float*)d_in[2];
    const float* w2      = (const float*)d_in[3];
    const float* b2      = (const float*)d_in[4];
    const float* gate1_w = (const float*)d_in[5];
    const float* e1_w    = (const float*)d_in[6];
    const float* e1_b    = (const float*)d_in[7];
    const float* gate2_w = (const float*)d_in[8];
    const float* e2_w    = (const float*)d_in[9];
    const float* e2_b    = (const float*)d_in[10];
    const int*   ei      = (const int*)d_in[11];
    const int*   nodes   = (const int*)d_in[12];

    const int n    = in_sizes[0] / 256;      // 100000
    const int nE   = in_sizes[11] / 2;       // 3200000
    const int nsel = in_sizes[12];           // 4096
    const int M    = nsel * 50;              // 204800
    const int nb   = (n + NPB - 1) / NPB;    // 1563

    size_t off = 0;
    auto alloc = [&](size_t bytes) -> void* {
        void* p = (char*)d_ws + off;
        off += (bytes + 255) & ~(size_t)255;
        return p;
    };
    float*  dis    = (float*)alloc((size_t)n * 4);
    int*    needed = (int*)alloc((size_t)n * 4);
    int*    bhist  = (int*)alloc((size_t)nb * 4);
    int*    boffs  = (int*)alloc((size_t)(nb + 1) * 4);
    int*    gcur   = (int*)alloc((size_t)nb * 4);
    int*    keys   = (int*)alloc((size_t)nE * 4);
    __half* hw1h   = (__half*)alloc((size_t)n * 32 * 2);
    float*  hw2s   = (float*)alloc((size_t)n * 16 * 4);
    float*  h2     = (float*)alloc((size_t)n * 16 * 4);
    if (off > ws_size) return;

    float* out1 = (float*)d_out;              // [M,2]
    float* out2 = out1 + (size_t)M * 2;       // [M,32]

    zero_kernel<<<(n + 255) / 256, 256, 0, stream>>>(needed, n);
    zero_kernel<<<(nb + 255) / 256, 256, 0, stream>>>(bhist, nb);
    needed_kernel<<<(nsel + 255) / 256, 256, 0, stream>>>(nodes, needed, nsel);
    histA_kernel<<<(nE + 4095) / 4096, 256, 0, stream>>>(ei, bhist, nE, nb);
    scanB_kernel<<<1, 256, 0, stream>>>(bhist, boffs, gcur, nb);
    scatterC_kernel<<<(nE + BATCH - 1) / BATCH, 256, 0, stream>>>(ei, gcur, keys, nE, nb);
    disC2_kernel<<<nb, 256, 0, stream>>>(keys, boffs, dis, n);
    hw1s_kernel<<<(n + 31) / 32, 256, 0, stream>>>(x, w1, dis, hw1h, n);
    agg1_kernel<<<nb, 256, 0, stream>>>(hw1h, dis, keys, boffs, b1, w2, hw2s, n);
    agg2_kernel<<<nb, 256, 0, stream>>>(hw2s, dis, keys, boffs, needed, b2, h2, n);
    pair_moe_kernel<<<(M + 255) / 256, 256, 0, stream>>>(h2, nodes, gate1_w, e1_w, e1_b,
                                                         gate2_w, e2_w, e2_b, out1, out2, M);
}

// Round 8
// 291.016 us; speedup vs baseline: 2.9785x; 2.8414x over previous
//
#include <hip/hip_runtime.h>
#include <hip/hip_fp16.h>
#include <math.h>

// ---------------------------------------------------------------------------
// GCNSim: 2-layer GCN. Bucket sort -> per-node CSR -> per-node register gather
// (r1 skeleton: 32 lanes = 32 features per node, no LDS atomics).
// hw1h = fp16[(x@w1)*dis] rows of 64B; srcs[] = per-node-grouped neighbor ids.
// Layer-2 aggregation computed only for the 4096 selected nodes.
// ---------------------------------------------------------------------------

#define NPB 64
#define NB_PAD 2048
#define BATCH 16384
#define NSCAP 12288

__global__ void zero_kernel(int* __restrict__ p, int c) {
    int i = blockIdx.x * 256 + threadIdx.x;
    if (i < c) p[i] = 0;
}

// ---- Pass A: per-bucket edge histogram (LDS-aggregated)
__global__ __launch_bounds__(256) void histA_kernel(const int* __restrict__ ei,
                                                    int* __restrict__ bhist, int nE, int nb) {
    __shared__ int h[NB_PAD];
    int tid = threadIdx.x;
    for (int t = tid; t < nb; t += 256) h[t] = 0;
    __syncthreads();
    int base = blockIdx.x * 4096;
    for (int t = tid; t < 4096; t += 256) {
        int e = base + t;
        if (e < nE) atomicAdd(&h[ei[nE + e] >> 6], 1);
    }
    __syncthreads();
    for (int t = tid; t < nb; t += 256) { int c = h[t]; if (c) atomicAdd(&bhist[t], c); }
}

// ---- Pass B: exclusive scan of bucket counts -> boffs[nb+1], gcur copy
__global__ __launch_bounds__(256) void scanB_kernel(const int* __restrict__ bhist,
                                                    int* __restrict__ boffs,
                                                    int* __restrict__ gcur, int nb) {
    int t = threadIdx.x;
    int v[8], s = 0;
    #pragma unroll
    for (int i = 0; i < 8; ++i) { int c = t * 8 + i; v[i] = (c < nb) ? bhist[c] : 0; s += v[i]; }
    int lane = t & 63, wid = t >> 6;
    int incl = s;
    for (int d = 1; d < 64; d <<= 1) { int u = __shfl_up(incl, (unsigned)d, 64); if (lane >= d) incl += u; }
    __shared__ int ws[4];
    if (lane == 63) ws[wid] = incl;
    __syncthreads();
    int add = 0;
    for (int w = 0; w < wid; ++w) add += ws[w];
    incl += add;
    int excl = incl - s;
    #pragma unroll
    for (int i = 0; i < 8; ++i) {
        int c = t * 8 + i;
        if (c < nb) { boffs[c] = excl; gcur[c] = excl; }
        excl += v[i];
    }
    if (t == 0) boffs[nb] = ws[0] + ws[1] + ws[2] + ws[3];
}

// ---- Pass C: batch-sorted scatter of packed keys into bucket regions
__global__ __launch_bounds__(256) void scatterC_kernel(const int* __restrict__ ei,
                                                       int* __restrict__ gcur,
                                                       int* __restrict__ keys, int nE, int nb) {
    __shared__ unsigned short sidx[BATCH];   // 32 KB
    __shared__ int hist[NB_PAD];
    __shared__ int lstart[NB_PAD];
    __shared__ int cursor[NB_PAD];
    __shared__ int gbase[NB_PAD];
    __shared__ int ws2[4];
    int tid = threadIdx.x;
    int base = blockIdx.x * BATCH;
    int cnt = nE - base; if (cnt > BATCH) cnt = BATCH;
    for (int t = tid; t < nb; t += 256) hist[t] = 0;
    __syncthreads();
    for (int t = tid; t < cnt; t += 256)
        atomicAdd(&hist[ei[nE + base + t] >> 6], 1);
    __syncthreads();
    {
        int v[8], s = 0;
        #pragma unroll
        for (int i = 0; i < 8; ++i) { int c = tid * 8 + i; v[i] = (c < nb) ? hist[c] : 0; s += v[i]; }
        int lane = tid & 63, wid = tid >> 6;
        int incl = s;
        for (int d = 1; d < 64; d <<= 1) { int u = __shfl_up(incl, (unsigned)d, 64); if (lane >= d) incl += u; }
        if (lane == 63) ws2[wid] = incl;
        __syncthreads();
        int add = 0;
        for (int w = 0; w < wid; ++w) add += ws2[w];
        incl += add;
        int excl = incl - s;
        #pragma unroll
        for (int i = 0; i < 8; ++i) {
            int c = tid * 8 + i;
            if (c < nb) { lstart[c] = excl; cursor[c] = excl; }
            excl += v[i];
        }
    }
    __syncthreads();
    for (int t = tid; t < nb; t += 256) {
        int c = hist[t];
        gbase[t] = c ? atomicAdd(&gcur[t], c) : 0;
    }
    for (int t = tid; t < cnt; t += 256) {
        int b = ei[nE + base + t] >> 6;
        int pos = atomicAdd(&cursor[b], 1);
        sidx[pos] = (unsigned short)t;
    }
    __syncthreads();
    for (int j = tid; j < cnt; j += 256) {
        int e = sidx[j];
        int d = ei[nE + base + e];
        int srcv = ei[base + e];
        int b = d >> 6;
        keys[gbase[b] + (j - lstart[b])] = srcv | ((d & 63) << 17);
    }
}

// ---- nodesort: bucket -> per-node CSR (in-place via LDS), noffs, dis
__global__ __launch_bounds__(256) void nodesort_kernel(int* __restrict__ keys,
                                                       const int* __restrict__ boffs,
                                                       int* __restrict__ noffs,
                                                       float* __restrict__ dis,
                                                       int n, int nbuck) {
    __shared__ int kb[NSCAP];     // 48 KB
    __shared__ int cnt[NPB], cur[NPB];
    int tid = threadIdx.x, b = blockIdx.x;
    int off = boffs[b], end = boffs[b + 1];
    int m = end - off; if (m > NSCAP) m = NSCAP;   // astronomically improbable clamp
    if (tid < NPB) cnt[tid] = 0;
    __syncthreads();
    for (int t = tid; t < m; t += 256) {
        int k = keys[off + t];
        kb[t] = k;
        atomicAdd(&cnt[k >> 17], 1);
    }
    __syncthreads();
    if (tid < NPB) {   // wave 0: exclusive scan over 64 counts
        int v = cnt[tid];
        int incl = v;
        for (int d = 1; d < 64; d <<= 1) { int u = __shfl_up(incl, (unsigned)d, 64); if (tid >= d) incl += u; }
        int excl = incl - v;
        cur[tid] = excl;
        int node = b * NPB + tid;
        if (node < n) {
            noffs[node] = off + excl;
            dis[node] = rsqrtf((float)(v + 1));  // +1 self-loop
        }
    }
    __syncthreads();
    for (int t = tid; t < m; t += 256) {
        int k = kb[t];
        int pos = atomicAdd(&cur[k >> 17], 1);
        keys[off + pos] = k & 0x1FFFF;   // now node-grouped plain src ids
    }
    if (b == nbuck - 1 && tid == 0) noffs[n] = end;
}

// ---- hw1h = fp16[(x @ w1) * dis]  [N,256]x[256,32] -> [N,32] (64B rows)
__global__ __launch_bounds__(256) void hw1s_kernel(const float* __restrict__ x,
                                                   const float* __restrict__ w1,
                                                   const float* __restrict__ dis,
                                                   __half* __restrict__ hw1h, int n) {
    __shared__ float w1s[256 * 32];   // 32 KB
    __shared__ float xs[32 * 256];    // 32 KB
    int tid = threadIdx.x;
    for (int t = tid * 4; t < 8192; t += 1024)
        *(float4*)&w1s[t] = *(const float4*)&w1[t];
    int row0 = blockIdx.x * 32;
    for (int t = tid; t < 2048; t += 256) {
        int r = t >> 6, c = (t & 63) * 4;
        int row = row0 + r;
        if (row < n) *(float4*)&xs[r * 256 + c] = *(const float4*)&x[(size_t)row * 256 + c];
        else *(float4*)&xs[r * 256 + c] = make_float4(0.f, 0.f, 0.f, 0.f);
    }
    __syncthreads();
    int k = tid & 31, rg = tid >> 5;
    float a0 = 0.f, a1 = 0.f, a2 = 0.f, a3 = 0.f;
    #pragma unroll 4
    for (int c = 0; c < 256; c += 4) {
        float4 x0 = *(float4*)&xs[(rg * 4 + 0) * 256 + c];
        float4 x1 = *(float4*)&xs[(rg * 4 + 1) * 256 + c];
        float4 x2 = *(float4*)&xs[(rg * 4 + 2) * 256 + c];
        float4 x3 = *(float4*)&xs[(rg * 4 + 3) * 256 + c];
        float w0 = w1s[(c    ) * 32 + k];
        float w1v = w1s[(c + 1) * 32 + k];
        float w2v = w1s[(c + 2) * 32 + k];
        float w3 = w1s[(c + 3) * 32 + k];
        a0 += x0.x * w0 + x0.y * w1v + x0.z * w2v + x0.w * w3;
        a1 += x1.x * w0 + x1.y * w1v + x1.z * w2v + x1.w * w3;
        a2 += x2.x * w0 + x2.y * w1v + x2.z * w2v + x2.w * w3;
        a3 += x3.x * w0 + x3.y * w1v + x3.z * w2v + x3.w * w3;
    }
    int r0 = row0 + rg * 4;
    if (r0 + 0 < n) hw1h[(size_t)(r0 + 0) * 32 + k] = __float2half(a0 * dis[r0 + 0]);
    if (r0 + 1 < n) hw1h[(size_t)(r0 + 1) * 32 + k] = __float2half(a1 * dis[r0 + 1]);
    if (r0 + 2 < n) hw1h[(size_t)(r0 + 2) * 32 + k] = __float2half(a2 * dis[r0 + 2]);
    if (r0 + 3 < n) hw1h[(size_t)(r0 + 3) * 32 + k] = __float2half(a3 * dis[r0 + 3]);
}

// ---- gatherG1: per-node register gather (32 lanes = 32 features), ReLU -> h1h
__global__ __launch_bounds__(256) void gatherG1_kernel(const __half* __restrict__ hw1h,
                                                       const float* __restrict__ dis,
                                                       const int* __restrict__ srcs,
                                                       const int* __restrict__ noffs,
                                                       const float* __restrict__ b1,
                                                       __half* __restrict__ h1h, int n) {
    int tid = threadIdx.x;
    int g = tid >> 5, k = tid & 31;
    int node = blockIdx.x * 8 + g;
    if (node >= n) return;
    int off = noffs[node], end = noffs[node + 1];
    float acc = 0.f;
    int e = off;
    for (; e + 8 <= end; e += 8) {
        int s0 = srcs[e],     s1 = srcs[e + 1], s2 = srcs[e + 2], s3 = srcs[e + 3];
        int s4 = srcs[e + 4], s5 = srcs[e + 5], s6 = srcs[e + 6], s7 = srcs[e + 7];
        float v0 = __half2float(hw1h[(size_t)s0 * 32 + k]);
        float v1 = __half2float(hw1h[(size_t)s1 * 32 + k]);
        float v2 = __half2float(hw1h[(size_t)s2 * 32 + k]);
        float v3 = __half2float(hw1h[(size_t)s3 * 32 + k]);
        float v4 = __half2float(hw1h[(size_t)s4 * 32 + k]);
        float v5 = __half2float(hw1h[(size_t)s5 * 32 + k]);
        float v6 = __half2float(hw1h[(size_t)s6 * 32 + k]);
        float v7 = __half2float(hw1h[(size_t)s7 * 32 + k]);
        acc += ((v0 + v1) + (v2 + v3)) + ((v4 + v5) + (v6 + v7));
    }
    for (; e < end; ++e)
        acc += __half2float(hw1h[(size_t)srcs[e] * 32 + k]);
    float dn = dis[node];
    float self = __half2float(hw1h[(size_t)node * 32 + k]);
    float h = fmaxf(dn * (acc + self) + b1[k], 0.f);
    h1h[(size_t)node * 32 + k] = __float2half(h);
}

// ---- gemm2: hw2s = (h1 @ w2) * dis   [N,32]x[32,16] -> [N,16] f32
__global__ __launch_bounds__(256) void gemm2_kernel(const __half* __restrict__ h1h,
                                                    const float* __restrict__ w2,
                                                    const float* __restrict__ dis,
                                                    float* __restrict__ hw2s, int n) {
    __shared__ float w2s[512];
    __shared__ float h1s[16][33];
    int tid = threadIdx.x;
    for (int t = tid; t < 512; t += 256) w2s[t] = w2[t];
    int node0 = blockIdx.x * 16;
    for (int t = tid; t < 512; t += 256) {
        int r = t >> 5, c = t & 31;
        int nd = node0 + r;
        h1s[r][c] = (nd < n) ? __half2float(h1h[(size_t)nd * 32 + c]) : 0.f;
    }
    __syncthreads();
    int r = tid >> 4, j = tid & 15;
    int nd = node0 + r;
    if (nd < n) {
        float a = 0.f;
        #pragma unroll
        for (int c = 0; c < 32; ++c) a += h1s[r][c] * w2s[c * 16 + j];
        hw2s[(size_t)nd * 16 + j] = a * dis[nd];
    }
}

// ---- gatherG2: layer-2 aggregation for SELECTED nodes only (16 lanes/node)
__global__ __launch_bounds__(256) void gatherG2_kernel(const float* __restrict__ hw2s,
                                                       const float* __restrict__ dis,
                                                       const int* __restrict__ srcs,
                                                       const int* __restrict__ noffs,
                                                       const int* __restrict__ nodes,
                                                       const float* __restrict__ b2,
                                                       float* __restrict__ h2, int nsel, int n) {
    int tid = threadIdx.x;
    int slot = tid >> 4, j = tid & 15;
    int i = blockIdx.x * 16 + slot;
    if (i >= nsel) return;
    int node = nodes[i];
    int off = noffs[node], end = noffs[node + 1];
    float acc = 0.f;
    int e = off;
    for (; e + 4 <= end; e += 4) {
        int s0 = srcs[e], s1 = srcs[e + 1], s2 = srcs[e + 2], s3 = srcs[e + 3];
        float v0 = hw2s[(size_t)s0 * 16 + j];
        float v1 = hw2s[(size_t)s1 * 16 + j];
        float v2 = hw2s[(size_t)s2 * 16 + j];
        float v3 = hw2s[(size_t)s3 * 16 + j];
        acc += (v0 + v1) + (v2 + v3);
    }
    for (; e < end; ++e) acc += hw2s[(size_t)srcs[e] * 16 + j];
    h2[(size_t)node * 16 + j] = dis[node] * (acc + hw2s[(size_t)node * 16 + j]) + b2[j];
}

// ---- pairwise concat + MoE1 + MoE2 + log_softmax
__global__ __launch_bounds__(256) void pair_moe_kernel(const float* __restrict__ h2,
                                                       const int* __restrict__ nodes,
                                                       const float* __restrict__ gate1_w,
                                                       const float* __restrict__ e1_w,
                                                       const float* __restrict__ e1_b,
                                                       const float* __restrict__ gate2_w,
                                                       const float* __restrict__ e2_w,
                                                       const float* __restrict__ e2_b,
                                                       float* __restrict__ out1,
                                                       float* __restrict__ out2, int M) {
    __shared__ float hjs[50 * 16];
    __shared__ float g1s[32 * 4];
    __shared__ float e1ws[4 * 32 * 16];
    __shared__ float e1bs[4 * 16];
    __shared__ float g2s[16 * 4];
    __shared__ float e2ws[4 * 16 * 2];
    __shared__ float e2bs[4 * 2];
    int tid = threadIdx.x;
    for (int t = tid; t < 800; t += 256) { int j = t >> 4, c = t & 15; hjs[t] = h2[nodes[j] * 16 + c]; }
    for (int t = tid; t < 128; t += 256) g1s[t] = gate1_w[t];
    for (int t = tid; t < 2048; t += 256) e1ws[t] = e1_w[t];
    for (int t = tid; t < 64; t += 256) e1bs[t] = e1_b[t];
    for (int t = tid; t < 64; t += 256) g2s[t] = gate2_w[t];
    for (int t = tid; t < 128; t += 256) e2ws[t] = e2_w[t];
    if (tid < 8) e2bs[tid] = e2_b[tid];
    __syncthreads();

    int m = blockIdx.x * 256 + tid;
    if (m >= M) return;
    int i = m / 50, j = m - i * 50;

    float xs[32];
    int ni = nodes[i];
    float4 a0 = *(const float4*)&h2[ni * 16];
    float4 a1 = *(const float4*)&h2[ni * 16 + 4];
    float4 a2 = *(const float4*)&h2[ni * 16 + 8];
    float4 a3 = *(const float4*)&h2[ni * 16 + 12];
    xs[0]=a0.x; xs[1]=a0.y; xs[2]=a0.z; xs[3]=a0.w;
    xs[4]=a1.x; xs[5]=a1.y; xs[6]=a1.z; xs[7]=a1.w;
    xs[8]=a2.x; xs[9]=a2.y; xs[10]=a2.z; xs[11]=a2.w;
    xs[12]=a3.x; xs[13]=a3.y; xs[14]=a3.z; xs[15]=a3.w;
    #pragma unroll
    for (int c = 0; c < 16; ++c) xs[16 + c] = hjs[j * 16 + c];

    #pragma unroll
    for (int c = 0; c < 32; c += 4)
        *(float4*)&out2[(size_t)m * 32 + c] = make_float4(xs[c], xs[c+1], xs[c+2], xs[c+3]);

    float g[4] = {0.f, 0.f, 0.f, 0.f};
    #pragma unroll
    for (int c = 0; c < 32; ++c) {
        float xv = xs[c];
        #pragma unroll
        for (int e = 0; e < 4; ++e) g[e] += xv * g1s[c * 4 + e];
    }
    int idx = 0; float best = g[0];
    #pragma unroll
    for (int e = 1; e < 4; ++e) if (g[e] > best) { best = g[e]; idx = e; }
    float z[16];
    #pragma unroll
    for (int o = 0; o < 16; ++o) {
        float a = e1bs[idx * 16 + o];
        #pragma unroll
        for (int c = 0; c < 32; ++c) a += xs[c] * e1ws[(idx * 32 + c) * 16 + o];
        z[o] = fmaxf(a, 0.f);
    }

    float g2[4] = {0.f, 0.f, 0.f, 0.f};
    #pragma unroll
    for (int c = 0; c < 16; ++c) {
        float zv = z[c];
        #pragma unroll
        for (int e = 0; e < 4; ++e) g2[e] += zv * g2s[c * 4 + e];
    }
    int idx2 = 0; float best2 = g2[0];
    #pragma unroll
    for (int e = 1; e < 4; ++e) if (g2[e] > best2) { best2 = g2[e]; idx2 = e; }
    float z2[2];
    #pragma unroll
    for (int o = 0; o < 2; ++o) {
        float a = e2bs[idx2 * 2 + o];
        #pragma unroll
        for (int c = 0; c < 16; ++c) a += z[c] * e2ws[(idx2 * 16 + c) * 2 + o];
        z2[o] = a;
    }

    float mx = fmaxf(z2[0], z2[1]);
    float l = logf(expf(z2[0] - mx) + expf(z2[1] - mx));
    out1[(size_t)m * 2 + 0] = z2[0] - mx - l;
    out1[(size_t)m * 2 + 1] = z2[1] - mx - l;
}

extern "C" void kernel_launch(void* const* d_in, const int* in_sizes, int n_in,
                              void* d_out, int out_size, void* d_ws, size_t ws_size,
                              hipStream_t stream) {
    const float* x       = (const float*)d_in[0];
    const float* w1      = (const float*)d_in[1];
    const float* b1      = (const float*)d_in[2];
    const float* w2      = (const float*)d_in[3];
    const float* b2      = (const float*)d_in[4];
    const float* gate1_w = (const float*)d_in[5];
    const float* e1_w    = (const float*)d_in[6];
    const float* e1_b    = (const float*)d_in[7];
    const float* gate2_w = (const float*)d_in[8];
    const float* e2_w    = (const float*)d_in[9];
    const float* e2_b    = (const float*)d_in[10];
    const int*   ei      = (const int*)d_in[11];
    const int*   nodes   = (const int*)d_in[12];

    const int n    = in_sizes[0] / 256;      // 100000
    const int nE   = in_sizes[11] / 2;       // 3200000
    const int nsel = in_sizes[12];           // 4096
    const int M    = nsel * 50;              // 204800
    const int nb   = (n + NPB - 1) / NPB;    // 1563

    size_t off = 0;
    auto alloc = [&](size_t bytes) -> void* {
        void* p = (char*)d_ws + off;
        off += (bytes + 255) & ~(size_t)255;
        return p;
    };
    float*  dis    = (float*)alloc((size_t)n * 4);
    int*    bhist  = (int*)alloc((size_t)nb * 4);
    int*    boffs  = (int*)alloc((size_t)(nb + 1) * 4);
    int*    gcur   = (int*)alloc((size_t)nb * 4);
    int*    noffs  = (int*)alloc((size_t)(n + 1) * 4);
    int*    keys   = (int*)alloc((size_t)nE * 4);   // becomes srcs after nodesort
    __half* hw1h   = (__half*)alloc((size_t)n * 32 * 2);
    __half* h1h    = (__half*)alloc((size_t)n * 32 * 2);
    float*  hw2s   = (float*)alloc((size_t)n * 16 * 4);
    float*  h2     = (float*)alloc((size_t)n * 16 * 4);
    if (off > ws_size) return;

    float* out1 = (float*)d_out;              // [M,2]
    float* out2 = out1 + (size_t)M * 2;       // [M,32]

    zero_kernel<<<(nb + 255) / 256, 256, 0, stream>>>(bhist, nb);
    histA_kernel<<<(nE + 4095) / 4096, 256, 0, stream>>>(ei, bhist, nE, nb);
    scanB_kernel<<<1, 256, 0, stream>>>(bhist, boffs, gcur, nb);
    scatterC_kernel<<<(nE + BATCH - 1) / BATCH, 256, 0, stream>>>(ei, gcur, keys, nE, nb);
    nodesort_kernel<<<nb, 256, 0, stream>>>(keys, boffs, noffs, dis, n, nb);
    hw1s_kernel<<<(n + 31) / 32, 256, 0, stream>>>(x, w1, dis, hw1h, n);
    gatherG1_kernel<<<(n + 7) / 8, 256, 0, stream>>>(hw1h, dis, keys, noffs, b1, h1h, n);
    gemm2_kernel<<<(n + 15) / 16, 256, 0, stream>>>(h1h, w2, dis, hw2s, n);
    gatherG2_kernel<<<(nsel + 15) / 16, 256, 0, stream>>>(hw2s, dis, keys, noffs, nodes, b2,
                                                          h2, nsel, n);
    pair_moe_kernel<<<(M + 255) / 256, 256, 0, stream>>>(h2, nodes, gate1_w, e1_w, e1_b,
                                                         gate2_w, e2_w, e2_b, out1, out2, M);
}

// Round 9
// 279.596 us; speedup vs baseline: 3.1002x; 1.0408x over previous
//
#include <hip/hip_runtime.h>
#include <hip/hip_fp16.h>
#include <math.h>

// ---------------------------------------------------------------------------
// GCNSim: 2-layer GCN. Bucket sort -> per-node CSR -> per-node register gather
// (32 lanes = 32 features per node, no LDS atomics).
// hw1h = fp16[(x@w1)*dis] rows of 64B; srcs[] = per-node-grouped neighbor ids.
// hw1s: register-blocked GEMM (8 rows x 4 k per thread, K-chunked LDS).
// Layer-2 aggregation computed only for the 4096 selected nodes.
// ---------------------------------------------------------------------------

#define NPB 64
#define NB_PAD 2048
#define BATCH 16384
#define NSCAP 12288

__global__ void zero_kernel(int* __restrict__ p, int c) {
    int i = blockIdx.x * 256 + threadIdx.x;
    if (i < c) p[i] = 0;
}

// ---- Pass A: per-bucket edge histogram (LDS-aggregated)
__global__ __launch_bounds__(256) void histA_kernel(const int* __restrict__ ei,
                                                    int* __restrict__ bhist, int nE, int nb) {
    __shared__ int h[NB_PAD];
    int tid = threadIdx.x;
    for (int t = tid; t < nb; t += 256) h[t] = 0;
    __syncthreads();
    int base = blockIdx.x * 4096;
    for (int t = tid; t < 4096; t += 256) {
        int e = base + t;
        if (e < nE) atomicAdd(&h[ei[nE + e] >> 6], 1);
    }
    __syncthreads();
    for (int t = tid; t < nb; t += 256) { int c = h[t]; if (c) atomicAdd(&bhist[t], c); }
}

// ---- Pass B: exclusive scan of bucket counts -> boffs[nb+1], gcur copy
__global__ __launch_bounds__(256) void scanB_kernel(const int* __restrict__ bhist,
                                                    int* __restrict__ boffs,
                                                    int* __restrict__ gcur, int nb) {
    int t = threadIdx.x;
    int v[8], s = 0;
    #pragma unroll
    for (int i = 0; i < 8; ++i) { int c = t * 8 + i; v[i] = (c < nb) ? bhist[c] : 0; s += v[i]; }
    int lane = t & 63, wid = t >> 6;
    int incl = s;
    for (int d = 1; d < 64; d <<= 1) { int u = __shfl_up(incl, (unsigned)d, 64); if (lane >= d) incl += u; }
    __shared__ int ws[4];
    if (lane == 63) ws[wid] = incl;
    __syncthreads();
    int add = 0;
    for (int w = 0; w < wid; ++w) add += ws[w];
    incl += add;
    int excl = incl - s;
    #pragma unroll
    for (int i = 0; i < 8; ++i) {
        int c = t * 8 + i;
        if (c < nb) { boffs[c] = excl; gcur[c] = excl; }
        excl += v[i];
    }
    if (t == 0) boffs[nb] = ws[0] + ws[1] + ws[2] + ws[3];
}

// ---- Pass C: batch-sorted scatter of packed keys into bucket regions
__global__ __launch_bounds__(256) void scatterC_kernel(const int* __restrict__ ei,
                                                       int* __restrict__ gcur,
                                                       int* __restrict__ keys, int nE, int nb) {
    __shared__ unsigned short sidx[BATCH];   // 32 KB
    __shared__ int hist[NB_PAD];
    __shared__ int lstart[NB_PAD];
    __shared__ int cursor[NB_PAD];
    __shared__ int gbase[NB_PAD];
    __shared__ int ws2[4];
    int tid = threadIdx.x;
    int base = blockIdx.x * BATCH;
    int cnt = nE - base; if (cnt > BATCH) cnt = BATCH;
    for (int t = tid; t < nb; t += 256) hist[t] = 0;
    __syncthreads();
    for (int t = tid; t < cnt; t += 256)
        atomicAdd(&hist[ei[nE + base + t] >> 6], 1);
    __syncthreads();
    {
        int v[8], s = 0;
        #pragma unroll
        for (int i = 0; i < 8; ++i) { int c = tid * 8 + i; v[i] = (c < nb) ? hist[c] : 0; s += v[i]; }
        int lane = tid & 63, wid = tid >> 6;
        int incl = s;
        for (int d = 1; d < 64; d <<= 1) { int u = __shfl_up(incl, (unsigned)d, 64); if (lane >= d) incl += u; }
        if (lane == 63) ws2[wid] = incl;
        __syncthreads();
        int add = 0;
        for (int w = 0; w < wid; ++w) add += ws2[w];
        incl += add;
        int excl = incl - s;
        #pragma unroll
        for (int i = 0; i < 8; ++i) {
            int c = tid * 8 + i;
            if (c < nb) { lstart[c] = excl; cursor[c] = excl; }
            excl += v[i];
        }
    }
    __syncthreads();
    for (int t = tid; t < nb; t += 256) {
        int c = hist[t];
        gbase[t] = c ? atomicAdd(&gcur[t], c) : 0;
    }
    for (int t = tid; t < cnt; t += 256) {
        int b = ei[nE + base + t] >> 6;
        int pos = atomicAdd(&cursor[b], 1);
        sidx[pos] = (unsigned short)t;
    }
    __syncthreads();
    for (int j = tid; j < cnt; j += 256) {
        int e = sidx[j];
        int d = ei[nE + base + e];
        int srcv = ei[base + e];
        int b = d >> 6;
        keys[gbase[b] + (j - lstart[b])] = srcv | ((d & 63) << 17);
    }
}

// ---- nodesort: bucket -> per-node CSR (in-place via LDS), noffs, dis
__global__ __launch_bounds__(256) void nodesort_kernel(int* __restrict__ keys,
                                                       const int* __restrict__ boffs,
                                                       int* __restrict__ noffs,
                                                       float* __restrict__ dis,
                                                       int n, int nbuck) {
    __shared__ int kb[NSCAP];     // 48 KB
    __shared__ int cnt[NPB], cur[NPB];
    int tid = threadIdx.x, b = blockIdx.x;
    int off = boffs[b], end = boffs[b + 1];
    int m = end - off; if (m > NSCAP) m = NSCAP;   // astronomically improbable clamp
    if (tid < NPB) cnt[tid] = 0;
    __syncthreads();
    for (int t = tid; t < m; t += 256) {
        int k = keys[off + t];
        kb[t] = k;
        atomicAdd(&cnt[k >> 17], 1);
    }
    __syncthreads();
    if (tid < NPB) {   // wave 0: exclusive scan over 64 counts
        int v = cnt[tid];
        int incl = v;
        for (int d = 1; d < 64; d <<= 1) { int u = __shfl_up(incl, (unsigned)d, 64); if (tid >= d) incl += u; }
        int excl = incl - v;
        cur[tid] = excl;
        int node = b * NPB + tid;
        if (node < n) {
            noffs[node] = off + excl;
            dis[node] = rsqrtf((float)(v + 1));  // +1 self-loop
        }
    }
    __syncthreads();
    for (int t = tid; t < m; t += 256) {
        int k = kb[t];
        int pos = atomicAdd(&cur[k >> 17], 1);
        keys[off + pos] = k & 0x1FFFF;   // now node-grouped plain src ids
    }
    if (b == nbuck - 1 && tid == 0) noffs[n] = end;
}

// ---- hw1h = fp16[(x @ w1) * dis]: register-blocked GEMM.
// 256 rows/block; thread = 8 rows x 4 k; K chunked x32 through LDS.
__global__ __launch_bounds__(256) void hw1s_kernel(const float* __restrict__ x,
                                                   const float* __restrict__ w1,
                                                   const float* __restrict__ dis,
                                                   __half* __restrict__ hw1h, int n) {
    __shared__ float xs[32 * 258];   // c-major [c][row], 33 KB, bank=(2c+row)%32
    __shared__ float w1s[32 * 32];   // [c][k] chunk, 4 KB
    int tid = threadIdx.x;
    int row0 = blockIdx.x * 256;
    int rt = tid & 31, kt = tid >> 5;   // 32 row-threads x 8 k-groups (4 k each)
    float acc[8][4];
    #pragma unroll
    for (int i = 0; i < 8; ++i) {
        #pragma unroll
        for (int j = 0; j < 4; ++j) acc[i][j] = 0.f;
    }

    for (int ch = 0; ch < 8; ++ch) {
        int cc0 = ch * 32;
        __syncthreads();   // previous chunk's compute done
        #pragma unroll
        for (int i = 0; i < 8; ++i) {
            int gid = i * 256 + tid;
            int r = gid >> 3, c4 = (gid & 7) << 2;
            int row = row0 + r;
            float4 v = (row < n) ? *(const float4*)&x[(size_t)row * 256 + cc0 + c4]
                                 : make_float4(0.f, 0.f, 0.f, 0.f);
            xs[(c4 + 0) * 258 + r] = v.x;
            xs[(c4 + 1) * 258 + r] = v.y;
            xs[(c4 + 2) * 258 + r] = v.z;
            xs[(c4 + 3) * 258 + r] = v.w;
        }
        {
            int c = tid >> 3, k4 = (tid & 7) << 2;
            *(float4*)&w1s[c * 32 + k4] = *(const float4*)&w1[(size_t)(cc0 + c) * 32 + k4];
        }
        __syncthreads();
        #pragma unroll 4
        for (int c = 0; c < 32; ++c) {
            float4 wv = *(float4*)&w1s[c * 32 + kt * 4];
            float xv[8];
            #pragma unroll
            for (int i = 0; i < 8; ++i) xv[i] = xs[c * 258 + rt + 32 * i];
            #pragma unroll
            for (int i = 0; i < 8; ++i) {
                acc[i][0] = fmaf(xv[i], wv.x, acc[i][0]);
                acc[i][1] = fmaf(xv[i], wv.y, acc[i][1]);
                acc[i][2] = fmaf(xv[i], wv.z, acc[i][2]);
                acc[i][3] = fmaf(xv[i], wv.w, acc[i][3]);
            }
        }
    }
    #pragma unroll
    for (int i = 0; i < 8; ++i) {
        int row = row0 + rt + 32 * i;
        if (row < n) {
            float dn = dis[row];
            __half2 h01 = __floats2half2_rn(acc[i][0] * dn, acc[i][1] * dn);
            __half2 h23 = __floats2half2_rn(acc[i][2] * dn, acc[i][3] * dn);
            __half2* dst = (__half2*)&hw1h[(size_t)row * 32 + kt * 4];
            dst[0] = h01; dst[1] = h23;
        }
    }
}

// ---- gatherG1: per-node register gather (32 lanes = 32 features), ReLU -> h1h
__global__ __launch_bounds__(256) void gatherG1_kernel(const __half* __restrict__ hw1h,
                                                       const float* __restrict__ dis,
                                                       const int* __restrict__ srcs,
                                                       const int* __restrict__ noffs,
                                                       const float* __restrict__ b1,
                                                       __half* __restrict__ h1h, int n) {
    int tid = threadIdx.x;
    int g = tid >> 5, k = tid & 31;
    int node = blockIdx.x * 8 + g;
    if (node >= n) return;
    int off = noffs[node], end = noffs[node + 1];
    float acc = 0.f;
    int e = off;
    for (; e + 8 <= end; e += 8) {
        int s0 = srcs[e],     s1 = srcs[e + 1], s2 = srcs[e + 2], s3 = srcs[e + 3];
        int s4 = srcs[e + 4], s5 = srcs[e + 5], s6 = srcs[e + 6], s7 = srcs[e + 7];
        float v0 = __half2float(hw1h[(size_t)s0 * 32 + k]);
        float v1 = __half2float(hw1h[(size_t)s1 * 32 + k]);
        float v2 = __half2float(hw1h[(size_t)s2 * 32 + k]);
        float v3 = __half2float(hw1h[(size_t)s3 * 32 + k]);
        float v4 = __half2float(hw1h[(size_t)s4 * 32 + k]);
        float v5 = __half2float(hw1h[(size_t)s5 * 32 + k]);
        float v6 = __half2float(hw1h[(size_t)s6 * 32 + k]);
        float v7 = __half2float(hw1h[(size_t)s7 * 32 + k]);
        acc += ((v0 + v1) + (v2 + v3)) + ((v4 + v5) + (v6 + v7));
    }
    for (; e < end; ++e)
        acc += __half2float(hw1h[(size_t)srcs[e] * 32 + k]);
    float dn = dis[node];
    float self = __half2float(hw1h[(size_t)node * 32 + k]);
    float h = fmaxf(dn * (acc + self) + b1[k], 0.f);
    h1h[(size_t)node * 32 + k] = __float2half(h);
}

// ---- gemm2: hw2s = (h1 @ w2) * dis   [N,32]x[32,16] -> [N,16] f32
__global__ __launch_bounds__(256) void gemm2_kernel(const __half* __restrict__ h1h,
                                                    const float* __restrict__ w2,
                                                    const float* __restrict__ dis,
                                                    float* __restrict__ hw2s, int n) {
    __shared__ float w2s[512];
    __shared__ float h1s[16][33];
    int tid = threadIdx.x;
    for (int t = tid; t < 512; t += 256) w2s[t] = w2[t];
    int node0 = blockIdx.x * 16;
    for (int t = tid; t < 512; t += 256) {
        int r = t >> 5, c = t & 31;
        int nd = node0 + r;
        h1s[r][c] = (nd < n) ? __half2float(h1h[(size_t)nd * 32 + c]) : 0.f;
    }
    __syncthreads();
    int r = tid >> 4, j = tid & 15;
    int nd = node0 + r;
    if (nd < n) {
        float a = 0.f;
        #pragma unroll
        for (int c = 0; c < 32; ++c) a += h1s[r][c] * w2s[c * 16 + j];
        hw2s[(size_t)nd * 16 + j] = a * dis[nd];
    }
}

// ---- gatherG2: layer-2 aggregation for SELECTED nodes only (16 lanes/node)
__global__ __launch_bounds__(256) void gatherG2_kernel(const float* __restrict__ hw2s,
                                                       const float* __restrict__ dis,
                                                       const int* __restrict__ srcs,
                                                       const int* __restrict__ noffs,
                                                       const int* __restrict__ nodes,
                                                       const float* __restrict__ b2,
                                                       float* __restrict__ h2, int nsel, int n) {
    int tid = threadIdx.x;
    int slot = tid >> 4, j = tid & 15;
    int i = blockIdx.x * 16 + slot;
    if (i >= nsel) return;
    int node = nodes[i];
    int off = noffs[node], end = noffs[node + 1];
    float acc = 0.f;
    int e = off;
    for (; e + 4 <= end; e += 4) {
        int s0 = srcs[e], s1 = srcs[e + 1], s2 = srcs[e + 2], s3 = srcs[e + 3];
        float v0 = hw2s[(size_t)s0 * 16 + j];
        float v1 = hw2s[(size_t)s1 * 16 + j];
        float v2 = hw2s[(size_t)s2 * 16 + j];
        float v3 = hw2s[(size_t)s3 * 16 + j];
        acc += (v0 + v1) + (v2 + v3);
    }
    for (; e < end; ++e) acc += hw2s[(size_t)srcs[e] * 16 + j];
    h2[(size_t)node * 16 + j] = dis[node] * (acc + hw2s[(size_t)node * 16 + j]) + b2[j];
}

// ---- pairwise concat + MoE1 + MoE2 + log_softmax
__global__ __launch_bounds__(256) void pair_moe_kernel(const float* __restrict__ h2,
                                                       const int* __restrict__ nodes,
                                                       const float* __restrict__ gate1_w,
                                                       const float* __restrict__ e1_w,
                                                       const float* __restrict__ e1_b,
                                                       const float* __restrict__ gate2_w,
                                                       const float* __restrict__ e2_w,
                                                       const float* __restrict__ e2_b,
                                                       float* __restrict__ out1,
                                                       float* __restrict__ out2, int M) {
    __shared__ float hjs[50 * 16];
    __shared__ float g1s[32 * 4];
    __shared__ float e1ws[4 * 32 * 16];
    __shared__ float e1bs[4 * 16];
    __shared__ float g2s[16 * 4];
    __shared__ float e2ws[4 * 16 * 2];
    __shared__ float e2bs[4 * 2];
    int tid = threadIdx.x;
    for (int t = tid; t < 800; t += 256) { int j = t >> 4, c = t & 15; hjs[t] = h2[nodes[j] * 16 + c]; }
    for (int t = tid; t < 128; t += 256) g1s[t] = gate1_w[t];
    for (int t = tid; t < 2048; t += 256) e1ws[t] = e1_w[t];
    for (int t = tid; t < 64; t += 256) e1bs[t] = e1_b[t];
    for (int t = tid; t < 64; t += 256) g2s[t] = gate2_w[t];
    for (int t = tid; t < 128; t += 256) e2ws[t] = e2_w[t];
    if (tid < 8) e2bs[tid] = e2_b[tid];
    __syncthreads();

    int m = blockIdx.x * 256 + tid;
    if (m >= M) return;
    int i = m / 50, j = m - i * 50;

    float xs[32];
    int ni = nodes[i];
    float4 a0 = *(const float4*)&h2[ni * 16];
    float4 a1 = *(const float4*)&h2[ni * 16 + 4];
    float4 a2 = *(const float4*)&h2[ni * 16 + 8];
    float4 a3 = *(const float4*)&h2[ni * 16 + 12];
    xs[0]=a0.x; xs[1]=a0.y; xs[2]=a0.z; xs[3]=a0.w;
    xs[4]=a1.x; xs[5]=a1.y; xs[6]=a1.z; xs[7]=a1.w;
    xs[8]=a2.x; xs[9]=a2.y; xs[10]=a2.z; xs[11]=a2.w;
    xs[12]=a3.x; xs[13]=a3.y; xs[14]=a3.z; xs[15]=a3.w;
    #pragma unroll
    for (int c = 0; c < 16; ++c) xs[16 + c] = hjs[j * 16 + c];

    #pragma unroll
    for (int c = 0; c < 32; c += 4)
        *(float4*)&out2[(size_t)m * 32 + c] = make_float4(xs[c], xs[c+1], xs[c+2], xs[c+3]);

    float g[4] = {0.f, 0.f, 0.f, 0.f};
    #pragma unroll
    for (int c = 0; c < 32; ++c) {
        float xv = xs[c];
        #pragma unroll
        for (int e = 0; e < 4; ++e) g[e] += xv * g1s[c * 4 + e];
    }
    int idx = 0; float best = g[0];
    #pragma unroll
    for (int e = 1; e < 4; ++e) if (g[e] > best) { best = g[e]; idx = e; }
    float z[16];
    #pragma unroll
    for (int o = 0; o < 16; ++o) {
        float a = e1bs[idx * 16 + o];
        #pragma unroll
        for (int c = 0; c < 32; ++c) a += xs[c] * e1ws[(idx * 32 + c) * 16 + o];
        z[o] = fmaxf(a, 0.f);
    }

    float g2[4] = {0.f, 0.f, 0.f, 0.f};
    #pragma unroll
    for (int c = 0; c < 16; ++c) {
        float zv = z[c];
        #pragma unroll
        for (int e = 0; e < 4; ++e) g2[e] += zv * g2s[c * 4 + e];
    }
    int idx2 = 0; float best2 = g2[0];
    #pragma unroll
    for (int e = 1; e < 4; ++e) if (g2[e] > best2) { best2 = g2[e]; idx2 = e; }
    float z2[2];
    #pragma unroll
    for (int o = 0; o < 2; ++o) {
        float a = e2bs[idx2 * 2 + o];
        #pragma unroll
        for (int c = 0; c < 16; ++c) a += z[c] * e2ws[(idx2 * 16 + c) * 2 + o];
        z2[o] = a;
    }

    float mx = fmaxf(z2[0], z2[1]);
    float l = logf(expf(z2[0] - mx) + expf(z2[1] - mx));
    out1[(size_t)m * 2 + 0] = z2[0] - mx - l;
    out1[(size_t)m * 2 + 1] = z2[1] - mx - l;
}

extern "C" void kernel_launch(void* const* d_in, const int* in_sizes, int n_in,
                              void* d_out, int out_size, void* d_ws, size_t ws_size,
                              hipStream_t stream) {
    const float* x       = (const float*)d_in[0];
    const float* w1      = (const float*)d_in[1];
    const float* b1      = (const float*)d_in[2];
    const float* w2      = (const float*)d_in[3];
    const float* b2      = (const float*)d_in[4];
    const float* gate1_w = (const float*)d_in[5];
    const float* e1_w    = (const float*)d_in[6];
    const float* e1_b    = (const float*)d_in[7];
    const float* gate2_w = (const float*)d_in[8];
    const float* e2_w    = (const float*)d_in[9];
    const float* e2_b    = (const float*)d_in[10];
    const int*   ei      = (const int*)d_in[11];
    const int*   nodes   = (const int*)d_in[12];

    const int n    = in_sizes[0] / 256;      // 100000
    const int nE   = in_sizes[11] / 2;       // 3200000
    const int nsel = in_sizes[12];           // 4096
    const int M    = nsel * 50;              // 204800
    const int nb   = (n + NPB - 1) / NPB;    // 1563

    size_t off = 0;
    auto alloc = [&](size_t bytes) -> void* {
        void* p = (char*)d_ws + off;
        off += (bytes + 255) & ~(size_t)255;
        return p;
    };
    float*  dis    = (float*)alloc((size_t)n * 4);
    int*    bhist  = (int*)alloc((size_t)nb * 4);
    int*    boffs  = (int*)alloc((size_t)(nb + 1) * 4);
    int*    gcur   = (int*)alloc((size_t)nb * 4);
    int*    noffs  = (int*)alloc((size_t)(n + 1) * 4);
    int*    keys   = (int*)alloc((size_t)nE * 4);   // becomes srcs after nodesort
    __half* hw1h   = (__half*)alloc((size_t)n * 32 * 2);
    __half* h1h    = (__half*)alloc((size_t)n * 32 * 2);
    float*  hw2s   = (float*)alloc((size_t)n * 16 * 4);
    float*  h2     = (float*)alloc((size_t)n * 16 * 4);
    if (off > ws_size) return;

    float* out1 = (float*)d_out;              // [M,2]
    float* out2 = out1 + (size_t)M * 2;       // [M,32]

    zero_kernel<<<(nb + 255) / 256, 256, 0, stream>>>(bhist, nb);
    histA_kernel<<<(nE + 4095) / 4096, 256, 0, stream>>>(ei, bhist, nE, nb);
    scanB_kernel<<<1, 256, 0, stream>>>(bhist, boffs, gcur, nb);
    scatterC_kernel<<<(nE + BATCH - 1) / BATCH, 256, 0, stream>>>(ei, gcur, keys, nE, nb);
    nodesort_kernel<<<nb, 256, 0, stream>>>(keys, boffs, noffs, dis, n, nb);
    hw1s_kernel<<<(n + 255) / 256, 256, 0, stream>>>(x, w1, dis, hw1h, n);
    gatherG1_kernel<<<(n + 7) / 8, 256, 0, stream>>>(hw1h, dis, keys, noffs, b1, h1h, n);
    gemm2_kernel<<<(n + 15) / 16, 256, 0, stream>>>(h1h, w2, dis, hw2s, n);
    gatherG2_kernel<<<(nsel + 15) / 16, 256, 0, stream>>>(hw2s, dis, keys, noffs, nodes, b2,
                                                          h2, nsel, n);
    pair_moe_kernel<<<(M + 255) / 256, 256, 0, stream>>>(h2, nodes, gate1_w, e1_w, e1_b,
                                                         gate2_w, e2_w, e2_b, out1, out2, M);
}

// Round 10
// 241.231 us; speedup vs baseline: 3.5932x; 1.1590x over previous
//
#include <hip/hip_runtime.h>
#include <hip/hip_fp16.h>
#include <math.h>

// ---------------------------------------------------------------------------
// GCNSim: 2-layer GCN. Bucket sort -> per-node CSR -> per-node register gather
// (32 lanes = 32 features per node, no LDS atomics).
// hw1h = fp16[(x@w1)*dis] rows of 64B; srcs[] = per-node-grouped neighbor ids.
// scatterC: value-scatter into LDS (kbuf/kbk), coalesced write-out, 2 blocks/CU.
// Layer-2 aggregation computed only for the 4096 selected nodes.
// ---------------------------------------------------------------------------

#define NPB 64
#define NB_PAD 2048
#define BATCH 8192
#define NSCAP 12288

__global__ void zero_kernel(int* __restrict__ p, int c) {
    int i = blockIdx.x * 256 + threadIdx.x;
    if (i < c) p[i] = 0;
}

// ---- Pass A: per-bucket edge histogram (LDS-aggregated)
__global__ __launch_bounds__(256) void histA_kernel(const int* __restrict__ ei,
                                                    int* __restrict__ bhist, int nE, int nb) {
    __shared__ int h[NB_PAD];
    int tid = threadIdx.x;
    for (int t = tid; t < nb; t += 256) h[t] = 0;
    __syncthreads();
    int base = blockIdx.x * 4096;
    for (int t = tid; t < 4096; t += 256) {
        int e = base + t;
        if (e < nE) atomicAdd(&h[ei[nE + e] >> 6], 1);
    }
    __syncthreads();
    for (int t = tid; t < nb; t += 256) { int c = h[t]; if (c) atomicAdd(&bhist[t], c); }
}

// ---- Pass B: exclusive scan of bucket counts -> boffs[nb+1], gcur copy
__global__ __launch_bounds__(256) void scanB_kernel(const int* __restrict__ bhist,
                                                    int* __restrict__ boffs,
                                                    int* __restrict__ gcur, int nb) {
    int t = threadIdx.x;
    int v[8], s = 0;
    #pragma unroll
    for (int i = 0; i < 8; ++i) { int c = t * 8 + i; v[i] = (c < nb) ? bhist[c] : 0; s += v[i]; }
    int lane = t & 63, wid = t >> 6;
    int incl = s;
    for (int d = 1; d < 64; d <<= 1) { int u = __shfl_up(incl, (unsigned)d, 64); if (lane >= d) incl += u; }
    __shared__ int ws[4];
    if (lane == 63) ws[wid] = incl;
    __syncthreads();
    int add = 0;
    for (int w = 0; w < wid; ++w) add += ws[w];
    incl += add;
    int excl = incl - s;
    #pragma unroll
    for (int i = 0; i < 8; ++i) {
        int c = t * 8 + i;
        if (c < nb) { boffs[c] = excl; gcur[c] = excl; }
        excl += v[i];
    }
    if (t == 0) boffs[nb] = ws[0] + ws[1] + ws[2] + ws[3];
}

// ---- Pass C: value-scatter of packed keys into bucket regions.
// kbuf[pos] = src|ld<<17 (23 bits), kbk[pos] = bucket id. Write-out is
// coalesced LDS reads + segment-contiguous global writes (no global gathers).
__global__ __launch_bounds__(256) void scatterC_kernel(const int* __restrict__ ei,
                                                       int* __restrict__ gcur,
                                                       int* __restrict__ keys, int nE, int nb) {
    __shared__ int kbuf[BATCH];              // 32 KB
    __shared__ unsigned short kbk[BATCH];    // 16 KB
    __shared__ int lstart[NB_PAD];           // 8 KB (hist -> scanned in place)
    __shared__ int cursor[NB_PAD];           // 8 KB
    __shared__ int gbase[NB_PAD];            // 8 KB
    __shared__ int ws2[4];
    int tid = threadIdx.x;
    int base = blockIdx.x * BATCH;
    int cnt = nE - base; if (cnt > BATCH) cnt = BATCH;
    for (int t = tid; t < nb; t += 256) lstart[t] = 0;
    __syncthreads();
    for (int t = tid; t < cnt; t += 256)
        atomicAdd(&lstart[ei[nE + base + t] >> 6], 1);
    __syncthreads();
    {   // in-place exclusive scan of lstart; copy to cursor
        int v[8], s = 0;
        #pragma unroll
        for (int i = 0; i < 8; ++i) { int c = tid * 8 + i; v[i] = (c < nb) ? lstart[c] : 0; s += v[i]; }
        int lane = tid & 63, wid = tid >> 6;
        int incl = s;
        for (int d = 1; d < 64; d <<= 1) { int u = __shfl_up(incl, (unsigned)d, 64); if (lane >= d) incl += u; }
        if (lane == 63) ws2[wid] = incl;
        __syncthreads();
        int add = 0;
        for (int w = 0; w < wid; ++w) add += ws2[w];
        incl += add;
        int excl = incl - s;
        #pragma unroll
        for (int i = 0; i < 8; ++i) {
            int c = tid * 8 + i;
            if (c < nb) { lstart[c] = excl; cursor[c] = excl; }
            excl += v[i];
        }
    }
    __syncthreads();
    // reserve global space per bucket (count = next_lstart - lstart)
    for (int t = tid; t < nb; t += 256) {
        int e = (t == nb - 1) ? cnt : lstart[t + 1];
        int c = e - lstart[t];
        gbase[t] = c ? atomicAdd(&gcur[t], c) : 0;
    }
    // value-scatter into LDS, bucket-major
    for (int t = tid; t < cnt; t += 256) {
        int d = ei[nE + base + t];
        int s = ei[base + t];
        int b = d >> 6;
        int pos = atomicAdd(&cursor[b], 1);
        kbuf[pos] = s | ((d & 63) << 17);
        kbk[pos] = (unsigned short)b;
    }
    __syncthreads();
    // coalesced write-out
    for (int j = tid; j < cnt; j += 256) {
        int b = kbk[j];
        keys[gbase[b] + (j - lstart[b])] = kbuf[j];
    }
}

// ---- nodesort: bucket -> per-node CSR (in-place via LDS), noffs, dis
__global__ __launch_bounds__(256) void nodesort_kernel(int* __restrict__ keys,
                                                       const int* __restrict__ boffs,
                                                       int* __restrict__ noffs,
                                                       float* __restrict__ dis,
                                                       int n, int nbuck) {
    __shared__ int kb[NSCAP];     // 48 KB
    __shared__ int cnt[NPB], cur[NPB];
    int tid = threadIdx.x, b = blockIdx.x;
    int off = boffs[b], end = boffs[b + 1];
    int m = end - off; if (m > NSCAP) m = NSCAP;   // astronomically improbable clamp
    if (tid < NPB) cnt[tid] = 0;
    __syncthreads();
    for (int t = tid; t < m; t += 256) {
        int k = keys[off + t];
        kb[t] = k;
        atomicAdd(&cnt[k >> 17], 1);
    }
    __syncthreads();
    if (tid < NPB) {   // wave 0: exclusive scan over 64 counts
        int v = cnt[tid];
        int incl = v;
        for (int d = 1; d < 64; d <<= 1) { int u = __shfl_up(incl, (unsigned)d, 64); if (tid >= d) incl += u; }
        int excl = incl - v;
        cur[tid] = excl;
        int node = b * NPB + tid;
        if (node < n) {
            noffs[node] = off + excl;
            dis[node] = rsqrtf((float)(v + 1));  // +1 self-loop
        }
    }
    __syncthreads();
    for (int t = tid; t < m; t += 256) {
        int k = kb[t];
        int pos = atomicAdd(&cur[k >> 17], 1);
        keys[off + pos] = k & 0x1FFFF;   // now node-grouped plain src ids
    }
    if (b == nbuck - 1 && tid == 0) noffs[n] = end;
}

// ---- hw1h = fp16[(x @ w1) * dis]: register-blocked GEMM.
// 256 rows/block; thread = 8 rows x 4 k; K chunked x32 through LDS.
__global__ __launch_bounds__(256) void hw1s_kernel(const float* __restrict__ x,
                                                   const float* __restrict__ w1,
                                                   const float* __restrict__ dis,
                                                   __half* __restrict__ hw1h, int n) {
    __shared__ float xs[32 * 258];   // c-major [c][row], 33 KB, bank=(2c+row)%32
    __shared__ float w1s[32 * 32];   // [c][k] chunk, 4 KB
    int tid = threadIdx.x;
    int row0 = blockIdx.x * 256;
    int rt = tid & 31, kt = tid >> 5;   // 32 row-threads x 8 k-groups (4 k each)
    float acc[8][4];
    #pragma unroll
    for (int i = 0; i < 8; ++i) {
        #pragma unroll
        for (int j = 0; j < 4; ++j) acc[i][j] = 0.f;
    }

    for (int ch = 0; ch < 8; ++ch) {
        int cc0 = ch * 32;
        __syncthreads();   // previous chunk's compute done
        #pragma unroll
        for (int i = 0; i < 8; ++i) {
            int gid = i * 256 + tid;
            int r = gid >> 3, c4 = (gid & 7) << 2;
            int row = row0 + r;
            float4 v = (row < n) ? *(const float4*)&x[(size_t)row * 256 + cc0 + c4]
                                 : make_float4(0.f, 0.f, 0.f, 0.f);
            xs[(c4 + 0) * 258 + r] = v.x;
            xs[(c4 + 1) * 258 + r] = v.y;
            xs[(c4 + 2) * 258 + r] = v.z;
            xs[(c4 + 3) * 258 + r] = v.w;
        }
        {
            int c = tid >> 3, k4 = (tid & 7) << 2;
            *(float4*)&w1s[c * 32 + k4] = *(const float4*)&w1[(size_t)(cc0 + c) * 32 + k4];
        }
        __syncthreads();
        #pragma unroll 4
        for (int c = 0; c < 32; ++c) {
            float4 wv = *(float4*)&w1s[c * 32 + kt * 4];
            float xv[8];
            #pragma unroll
            for (int i = 0; i < 8; ++i) xv[i] = xs[c * 258 + rt + 32 * i];
            #pragma unroll
            for (int i = 0; i < 8; ++i) {
                acc[i][0] = fmaf(xv[i], wv.x, acc[i][0]);
                acc[i][1] = fmaf(xv[i], wv.y, acc[i][1]);
                acc[i][2] = fmaf(xv[i], wv.z, acc[i][2]);
                acc[i][3] = fmaf(xv[i], wv.w, acc[i][3]);
            }
        }
    }
    #pragma unroll
    for (int i = 0; i < 8; ++i) {
        int row = row0 + rt + 32 * i;
        if (row < n) {
            float dn = dis[row];
            __half2 h01 = __floats2half2_rn(acc[i][0] * dn, acc[i][1] * dn);
            __half2 h23 = __floats2half2_rn(acc[i][2] * dn, acc[i][3] * dn);
            __half2* dst = (__half2*)&hw1h[(size_t)row * 32 + kt * 4];
            dst[0] = h01; dst[1] = h23;
        }
    }
}

// ---- gatherG1: per-node register gather (32 lanes = 32 features), ReLU -> h1h
__global__ __launch_bounds__(256) void gatherG1_kernel(const __half* __restrict__ hw1h,
                                                       const float* __restrict__ dis,
                                                       const int* __restrict__ srcs,
                                                       const int* __restrict__ noffs,
                                                       const float* __restrict__ b1,
                                                       __half* __restrict__ h1h, int n) {
    int tid = threadIdx.x;
    int g = tid >> 5, k = tid & 31;
    int node = blockIdx.x * 8 + g;
    if (node >= n) return;
    int off = noffs[node], end = noffs[node + 1];
    float acc = 0.f;
    int e = off;
    for (; e + 8 <= end; e += 8) {
        int s0 = srcs[e],     s1 = srcs[e + 1], s2 = srcs[e + 2], s3 = srcs[e + 3];
        int s4 = srcs[e + 4], s5 = srcs[e + 5], s6 = srcs[e + 6], s7 = srcs[e + 7];
        float v0 = __half2float(hw1h[(size_t)s0 * 32 + k]);
        float v1 = __half2float(hw1h[(size_t)s1 * 32 + k]);
        float v2 = __half2float(hw1h[(size_t)s2 * 32 + k]);
        float v3 = __half2float(hw1h[(size_t)s3 * 32 + k]);
        float v4 = __half2float(hw1h[(size_t)s4 * 32 + k]);
        float v5 = __half2float(hw1h[(size_t)s5 * 32 + k]);
        float v6 = __half2float(hw1h[(size_t)s6 * 32 + k]);
        float v7 = __half2float(hw1h[(size_t)s7 * 32 + k]);
        acc += ((v0 + v1) + (v2 + v3)) + ((v4 + v5) + (v6 + v7));
    }
    for (; e < end; ++e)
        acc += __half2float(hw1h[(size_t)srcs[e] * 32 + k]);
    float dn = dis[node];
    float self = __half2float(hw1h[(size_t)node * 32 + k]);
    float h = fmaxf(dn * (acc + self) + b1[k], 0.f);
    h1h[(size_t)node * 32 + k] = __float2half(h);
}

// ---- gemm2: hw2s = (h1 @ w2) * dis   [N,32]x[32,16] -> [N,16] f32
__global__ __launch_bounds__(256) void gemm2_kernel(const __half* __restrict__ h1h,
                                                    const float* __restrict__ w2,
                                                    const float* __restrict__ dis,
                                                    float* __restrict__ hw2s, int n) {
    __shared__ float w2s[512];
    __shared__ float h1s[16][33];
    int tid = threadIdx.x;
    for (int t = tid; t < 512; t += 256) w2s[t] = w2[t];
    int node0 = blockIdx.x * 16;
    for (int t = tid; t < 512; t += 256) {
        int r = t >> 5, c = t & 31;
        int nd = node0 + r;
        h1s[r][c] = (nd < n) ? __half2float(h1h[(size_t)nd * 32 + c]) : 0.f;
    }
    __syncthreads();
    int r = tid >> 4, j = tid & 15;
    int nd = node0 + r;
    if (nd < n) {
        float a = 0.f;
        #pragma unroll
        for (int c = 0; c < 32; ++c) a += h1s[r][c] * w2s[c * 16 + j];
        hw2s[(size_t)nd * 16 + j] = a * dis[nd];
    }
}

// ---- gatherG2: layer-2 aggregation for SELECTED nodes only (16 lanes/node)
__global__ __launch_bounds__(256) void gatherG2_kernel(const float* __restrict__ hw2s,
                                                       const float* __restrict__ dis,
                                                       const int* __restrict__ srcs,
                                                       const int* __restrict__ noffs,
                                                       const int* __restrict__ nodes,
                                                       const float* __restrict__ b2,
                                                       float* __restrict__ h2, int nsel, int n) {
    int tid = threadIdx.x;
    int slot = tid >> 4, j = tid & 15;
    int i = blockIdx.x * 16 + slot;
    if (i >= nsel) return;
    int node = nodes[i];
    int off = noffs[node], end = noffs[node + 1];
    float acc = 0.f;
    int e = off;
    for (; e + 4 <= end; e += 4) {
        int s0 = srcs[e], s1 = srcs[e + 1], s2 = srcs[e + 2], s3 = srcs[e + 3];
        float v0 = hw2s[(size_t)s0 * 16 + j];
        float v1 = hw2s[(size_t)s1 * 16 + j];
        float v2 = hw2s[(size_t)s2 * 16 + j];
        float v3 = hw2s[(size_t)s3 * 16 + j];
        acc += (v0 + v1) + (v2 + v3);
    }
    for (; e < end; ++e) acc += hw2s[(size_t)srcs[e] * 16 + j];
    h2[(size_t)node * 16 + j] = dis[node] * (acc + hw2s[(size_t)node * 16 + j]) + b2[j];
}

// ---- pairwise concat + MoE1 + MoE2 + log_softmax
__global__ __launch_bounds__(256) void pair_moe_kernel(const float* __restrict__ h2,
                                                       const int* __restrict__ nodes,
                                                       const float* __restrict__ gate1_w,
                                                       const float* __restrict__ e1_w,
                                                       const float* __restrict__ e1_b,
                                                       const float* __restrict__ gate2_w,
                                                       const float* __restrict__ e2_w,
                                                       const float* __restrict__ e2_b,
                                                       float* __restrict__ out1,
                                                       float* __restrict__ out2, int M) {
    __shared__ float hjs[50 * 16];
    __shared__ float g1s[32 * 4];
    __shared__ float e1ws[4 * 32 * 16];
    __shared__ float e1bs[4 * 16];
    __shared__ float g2s[16 * 4];
    __shared__ float e2ws[4 * 16 * 2];
    __shared__ float e2bs[4 * 2];
    int tid = threadIdx.x;
    for (int t = tid; t < 800; t += 256) { int j = t >> 4, c = t & 15; hjs[t] = h2[nodes[j] * 16 + c]; }
    for (int t = tid; t < 128; t += 256) g1s[t] = gate1_w[t];
    for (int t = tid; t < 2048; t += 256) e1ws[t] = e1_w[t];
    for (int t = tid; t < 64; t += 256) e1bs[t] = e1_b[t];
    for (int t = tid; t < 64; t += 256) g2s[t] = gate2_w[t];
    for (int t = tid; t < 128; t += 256) e2ws[t] = e2_w[t];
    if (tid < 8) e2bs[tid] = e2_b[tid];
    __syncthreads();

    int m = blockIdx.x * 256 + tid;
    if (m >= M) return;
    int i = m / 50, j = m - i * 50;

    float xs[32];
    int ni = nodes[i];
    float4 a0 = *(const float4*)&h2[ni * 16];
    float4 a1 = *(const float4*)&h2[ni * 16 + 4];
    float4 a2 = *(const float4*)&h2[ni * 16 + 8];
    float4 a3 = *(const float4*)&h2[ni * 16 + 12];
    xs[0]=a0.x; xs[1]=a0.y; xs[2]=a0.z; xs[3]=a0.w;
    xs[4]=a1.x; xs[5]=a1.y; xs[6]=a1.z; xs[7]=a1.w;
    xs[8]=a2.x; xs[9]=a2.y; xs[10]=a2.z; xs[11]=a2.w;
    xs[12]=a3.x; xs[13]=a3.y; xs[14]=a3.z; xs[15]=a3.w;
    #pragma unroll
    for (int c = 0; c < 16; ++c) xs[16 + c] = hjs[j * 16 + c];

    #pragma unroll
    for (int c = 0; c < 32; c += 4)
        *(float4*)&out2[(size_t)m * 32 + c] = make_float4(xs[c], xs[c+1], xs[c+2], xs[c+3]);

    float g[4] = {0.f, 0.f, 0.f, 0.f};
    #pragma unroll
    for (int c = 0; c < 32; ++c) {
        float xv = xs[c];
        #pragma unroll
        for (int e = 0; e < 4; ++e) g[e] += xv * g1s[c * 4 + e];
    }
    int idx = 0; float best = g[0];
    #pragma unroll
    for (int e = 1; e < 4; ++e) if (g[e] > best) { best = g[e]; idx = e; }
    float z[16];
    #pragma unroll
    for (int o = 0; o < 16; ++o) {
        float a = e1bs[idx * 16 + o];
        #pragma unroll
        for (int c = 0; c < 32; ++c) a += xs[c] * e1ws[(idx * 32 + c) * 16 + o];
        z[o] = fmaxf(a, 0.f);
    }

    float g2[4] = {0.f, 0.f, 0.f, 0.f};
    #pragma unroll
    for (int c = 0; c < 16; ++c) {
        float zv = z[c];
        #pragma unroll
        for (int e = 0; e < 4; ++e) g2[e] += zv * g2s[c * 4 + e];
    }
    int idx2 = 0; float best2 = g2[0];
    #pragma unroll
    for (int e = 1; e < 4; ++e) if (g2[e] > best2) { best2 = g2[e]; idx2 = e; }
    float z2[2];
    #pragma unroll
    for (int o = 0; o < 2; ++o) {
        float a = e2bs[idx2 * 2 + o];
        #pragma unroll
        for (int c = 0; c < 16; ++c) a += z[c] * e2ws[(idx2 * 16 + c) * 2 + o];
        z2[o] = a;
    }

    float mx = fmaxf(z2[0], z2[1]);
    float l = logf(expf(z2[0] - mx) + expf(z2[1] - mx));
    out1[(size_t)m * 2 + 0] = z2[0] - mx - l;
    out1[(size_t)m * 2 + 1] = z2[1] - mx - l;
}

extern "C" void kernel_launch(void* const* d_in, const int* in_sizes, int n_in,
                              void* d_out, int out_size, void* d_ws, size_t ws_size,
                              hipStream_t stream) {
    const float* x       = (const float*)d_in[0];
    const float* w1      = (const float*)d_in[1];
    const float* b1      = (const float*)d_in[2];
    const float* w2      = (const float*)d_in[3];
    const float* b2      = (const float*)d_in[4];
    const float* gate1_w = (const float*)d_in[5];
    const float* e1_w    = (const float*)d_in[6];
    const float* e1_b    = (const float*)d_in[7];
    const float* gate2_w = (const float*)d_in[8];
    const float* e2_w    = (const float*)d_in[9];
    const float* e2_b    = (const float*)d_in[10];
    const int*   ei      = (const int*)d_in[11];
    const int*   nodes   = (const int*)d_in[12];

    const int n    = in_sizes[0] / 256;      // 100000
    const int nE   = in_sizes[11] / 2;       // 3200000
    const int nsel = in_sizes[12];           // 4096
    const int M    = nsel * 50;              // 204800
    const int nb   = (n + NPB - 1) / NPB;    // 1563

    size_t off = 0;
    auto alloc = [&](size_t bytes) -> void* {
        void* p = (char*)d_ws + off;
        off += (bytes + 255) & ~(size_t)255;
        return p;
    };
    float*  dis    = (float*)alloc((size_t)n * 4);
    int*    bhist  = (int*)alloc((size_t)nb * 4);
    int*    boffs  = (int*)alloc((size_t)(nb + 1) * 4);
    int*    gcur   = (int*)alloc((size_t)nb * 4);
    int*    noffs  = (int*)alloc((size_t)(n + 1) * 4);
    int*    keys   = (int*)alloc((size_t)nE * 4);   // becomes srcs after nodesort
    __half* hw1h   = (__half*)alloc((size_t)n * 32 * 2);
    __half* h1h    = (__half*)alloc((size_t)n * 32 * 2);
    float*  hw2s   = (float*)alloc((size_t)n * 16 * 4);
    float*  h2     = (float*)alloc((size_t)n * 16 * 4);
    if (off > ws_size) return;

    float* out1 = (float*)d_out;              // [M,2]
    float* out2 = out1 + (size_t)M * 2;       // [M,32]

    zero_kernel<<<(nb + 255) / 256, 256, 0, stream>>>(bhist, nb);
    histA_kernel<<<(nE + 4095) / 4096, 256, 0, stream>>>(ei, bhist, nE, nb);
    scanB_kernel<<<1, 256, 0, stream>>>(bhist, boffs, gcur, nb);
    scatterC_kernel<<<(nE + BATCH - 1) / BATCH, 256, 0, stream>>>(ei, gcur, keys, nE, nb);
    nodesort_kernel<<<nb, 256, 0, stream>>>(keys, boffs, noffs, dis, n, nb);
    hw1s_kernel<<<(n + 255) / 256, 256, 0, stream>>>(x, w1, dis, hw1h, n);
    gatherG1_kernel<<<(n + 7) / 8, 256, 0, stream>>>(hw1h, dis, keys, noffs, b1, h1h, n);
    gemm2_kernel<<<(n + 15) / 16, 256, 0, stream>>>(h1h, w2, dis, hw2s, n);
    gatherG2_kernel<<<(nsel + 15) / 16, 256, 0, stream>>>(hw2s, dis, keys, noffs, nodes, b2,
                                                          h2, nsel, n);
    pair_moe_kernel<<<(M + 255) / 256, 256, 0, stream>>>(h2, nodes, gate1_w, e1_w, e1_b,
                                                         gate2_w, e2_w, e2_b, out1, out2, M);
}

// Round 11
// 228.994 us; speedup vs baseline: 3.7852x; 1.0534x over previous
//
#include <hip/hip_runtime.h>
#include <hip/hip_fp16.h>
#include <math.h>

// ---------------------------------------------------------------------------
// GCNSim: 2-layer GCN. Bucket sort -> per-node CSR -> per-node register gather
// (32 lanes = 32 features per node, no LDS atomics).
// hw1h = fp16[(x@w1)*dis] rows of 64B; srcs[] = per-node-grouped neighbor ids.
// hw1s v3: thread=(row,khalf); w1 row via SGPR s_load (readfirstlane-forced);
// x via one ds_read_b32 per row*c. scatterC: LDS value-scatter, coalesced out.
// Layer-2 aggregation computed only for the 4096 selected nodes.
// ---------------------------------------------------------------------------

#define NPB 64
#define NB_PAD 2048
#define BATCH 8192
#define NSCAP 12288

__global__ void zero_kernel(int* __restrict__ p, int c) {
    int i = blockIdx.x * 256 + threadIdx.x;
    if (i < c) p[i] = 0;
}

// ---- Pass A: per-bucket edge histogram (LDS-aggregated)
__global__ __launch_bounds__(256) void histA_kernel(const int* __restrict__ ei,
                                                    int* __restrict__ bhist, int nE, int nb) {
    __shared__ int h[NB_PAD];
    int tid = threadIdx.x;
    for (int t = tid; t < nb; t += 256) h[t] = 0;
    __syncthreads();
    int base = blockIdx.x * 4096;
    for (int t = tid; t < 4096; t += 256) {
        int e = base + t;
        if (e < nE) atomicAdd(&h[ei[nE + e] >> 6], 1);
    }
    __syncthreads();
    for (int t = tid; t < nb; t += 256) { int c = h[t]; if (c) atomicAdd(&bhist[t], c); }
}

// ---- Pass B: exclusive scan of bucket counts -> boffs[nb+1], gcur copy
__global__ __launch_bounds__(256) void scanB_kernel(const int* __restrict__ bhist,
                                                    int* __restrict__ boffs,
                                                    int* __restrict__ gcur, int nb) {
    int t = threadIdx.x;
    int v[8], s = 0;
    #pragma unroll
    for (int i = 0; i < 8; ++i) { int c = t * 8 + i; v[i] = (c < nb) ? bhist[c] : 0; s += v[i]; }
    int lane = t & 63, wid = t >> 6;
    int incl = s;
    for (int d = 1; d < 64; d <<= 1) { int u = __shfl_up(incl, (unsigned)d, 64); if (lane >= d) incl += u; }
    __shared__ int ws[4];
    if (lane == 63) ws[wid] = incl;
    __syncthreads();
    int add = 0;
    for (int w = 0; w < wid; ++w) add += ws[w];
    incl += add;
    int excl = incl - s;
    #pragma unroll
    for (int i = 0; i < 8; ++i) {
        int c = t * 8 + i;
        if (c < nb) { boffs[c] = excl; gcur[c] = excl; }
        excl += v[i];
    }
    if (t == 0) boffs[nb] = ws[0] + ws[1] + ws[2] + ws[3];
}

// ---- Pass C: value-scatter of packed keys into bucket regions.
__global__ __launch_bounds__(256) void scatterC_kernel(const int* __restrict__ ei,
                                                       int* __restrict__ gcur,
                                                       int* __restrict__ keys, int nE, int nb) {
    __shared__ int kbuf[BATCH];              // 32 KB
    __shared__ unsigned short kbk[BATCH];    // 16 KB
    __shared__ int lstart[NB_PAD];           // 8 KB
    __shared__ int cursor[NB_PAD];           // 8 KB
    __shared__ int gbase[NB_PAD];            // 8 KB
    __shared__ int ws2[4];
    int tid = threadIdx.x;
    int base = blockIdx.x * BATCH;
    int cnt = nE - base; if (cnt > BATCH) cnt = BATCH;
    for (int t = tid; t < nb; t += 256) lstart[t] = 0;
    __syncthreads();
    for (int t = tid; t < cnt; t += 256)
        atomicAdd(&lstart[ei[nE + base + t] >> 6], 1);
    __syncthreads();
    {
        int v[8], s = 0;
        #pragma unroll
        for (int i = 0; i < 8; ++i) { int c = tid * 8 + i; v[i] = (c < nb) ? lstart[c] : 0; s += v[i]; }
        int lane = tid & 63, wid = tid >> 6;
        int incl = s;
        for (int d = 1; d < 64; d <<= 1) { int u = __shfl_up(incl, (unsigned)d, 64); if (lane >= d) incl += u; }
        if (lane == 63) ws2[wid] = incl;
        __syncthreads();
        int add = 0;
        for (int w = 0; w < wid; ++w) add += ws2[w];
        incl += add;
        int excl = incl - s;
        #pragma unroll
        for (int i = 0; i < 8; ++i) {
            int c = tid * 8 + i;
            if (c < nb) { lstart[c] = excl; cursor[c] = excl; }
            excl += v[i];
        }
    }
    __syncthreads();
    for (int t = tid; t < nb; t += 256) {
        int e = (t == nb - 1) ? cnt : lstart[t + 1];
        int c = e - lstart[t];
        gbase[t] = c ? atomicAdd(&gcur[t], c) : 0;
    }
    for (int t = tid; t < cnt; t += 256) {
        int d = ei[nE + base + t];
        int s = ei[base + t];
        int b = d >> 6;
        int pos = atomicAdd(&cursor[b], 1);
        kbuf[pos] = s | ((d & 63) << 17);
        kbk[pos] = (unsigned short)b;
    }
    __syncthreads();
    for (int j = tid; j < cnt; j += 256) {
        int b = kbk[j];
        keys[gbase[b] + (j - lstart[b])] = kbuf[j];
    }
}

// ---- nodesort: bucket -> per-node CSR (in-place via LDS), noffs, dis
__global__ __launch_bounds__(256) void nodesort_kernel(int* __restrict__ keys,
                                                       const int* __restrict__ boffs,
                                                       int* __restrict__ noffs,
                                                       float* __restrict__ dis,
                                                       int n, int nbuck) {
    __shared__ int kb[NSCAP];     // 48 KB
    __shared__ int cnt[NPB], cur[NPB];
    int tid = threadIdx.x, b = blockIdx.x;
    int off = boffs[b], end = boffs[b + 1];
    int m = end - off; if (m > NSCAP) m = NSCAP;
    if (tid < NPB) cnt[tid] = 0;
    __syncthreads();
    for (int t = tid; t < m; t += 256) {
        int k = keys[off + t];
        kb[t] = k;
        atomicAdd(&cnt[k >> 17], 1);
    }
    __syncthreads();
    if (tid < NPB) {
        int v = cnt[tid];
        int incl = v;
        for (int d = 1; d < 64; d <<= 1) { int u = __shfl_up(incl, (unsigned)d, 64); if (tid >= d) incl += u; }
        int excl = incl - v;
        cur[tid] = excl;
        int node = b * NPB + tid;
        if (node < n) {
            noffs[node] = off + excl;
            dis[node] = rsqrtf((float)(v + 1));
        }
    }
    __syncthreads();
    for (int t = tid; t < m; t += 256) {
        int k = kb[t];
        int pos = atomicAdd(&cur[k >> 17], 1);
        keys[off + pos] = k & 0x1FFFF;
    }
    if (b == nbuck - 1 && tid == 0) noffs[n] = end;
}

// ---- hw1h = fp16[(x @ w1) * dis]: thread = (row, khalf).
// w1 row read through SGPRs (uniform address via readfirstlane) -> s_load;
// inner loop = 1 ds_read_b32 + 16 v_fmac per c. 128 rows/block, grid 782.
__global__ __launch_bounds__(256) void hw1s_kernel(const float* __restrict__ x,
                                                   const float* __restrict__ w1,
                                                   const float* __restrict__ dis,
                                                   __half* __restrict__ hw1h, int n) {
    __shared__ float xs[32 * 130];   // [c][r], 16.6 KB; bank=(2c+r)%32
    int tid = threadIdx.x;
    int row0 = blockIdx.x * 128;
    int r = tid & 127;                 // row within block
    int khs = __builtin_amdgcn_readfirstlane((tid >> 7) * 16);  // wave-uniform k-half
    float acc[16];
    #pragma unroll
    for (int k = 0; k < 16; ++k) acc[k] = 0.f;

    for (int ch = 0; ch < 8; ++ch) {
        int cc0 = ch * 32;
        __syncthreads();   // previous chunk's compute done
        #pragma unroll
        for (int i = 0; i < 4; ++i) {
            int gid = i * 256 + tid;
            int rr = gid >> 3, c4 = (gid & 7) << 2;
            int row = row0 + rr;
            float4 v = (row < n) ? *(const float4*)&x[(size_t)row * 256 + cc0 + c4]
                                 : make_float4(0.f, 0.f, 0.f, 0.f);
            xs[(c4 + 0) * 130 + rr] = v.x;
            xs[(c4 + 1) * 130 + rr] = v.y;
            xs[(c4 + 2) * 130 + rr] = v.z;
            xs[(c4 + 3) * 130 + rr] = v.w;
        }
        __syncthreads();
        #pragma unroll 4
        for (int c = 0; c < 32; ++c) {
            float xv = xs[c * 130 + r];
            const float* wrow = &w1[(size_t)(cc0 + c) * 32 + khs];   // uniform -> s_load
            #pragma unroll
            for (int k = 0; k < 16; ++k)
                acc[k] = fmaf(xv, wrow[k], acc[k]);
        }
    }
    int row = row0 + r;
    if (row < n) {
        float dn = dis[row];
        __half2 h[8];
        #pragma unroll
        for (int k = 0; k < 8; ++k)
            h[k] = __floats2half2_rn(acc[2 * k] * dn, acc[2 * k + 1] * dn);
        float4* dst = (float4*)&hw1h[(size_t)row * 32 + khs];
        dst[0] = *(float4*)&h[0];
        dst[1] = *(float4*)&h[4];
    }
}

// ---- gatherG1: per-node register gather (32 lanes = 32 features), ReLU -> h1h
__global__ __launch_bounds__(256) void gatherG1_kernel(const __half* __restrict__ hw1h,
                                                       const float* __restrict__ dis,
                                                       const int* __restrict__ srcs,
                                                       const int* __restrict__ noffs,
                                                       const float* __restrict__ b1,
                                                       __half* __restrict__ h1h, int n) {
    int tid = threadIdx.x;
    int g = tid >> 5, k = tid & 31;
    int node = blockIdx.x * 8 + g;
    if (node >= n) return;
    int off = noffs[node], end = noffs[node + 1];
    float acc = 0.f;
    int e = off;
    for (; e + 8 <= end; e += 8) {
        int s0 = srcs[e],     s1 = srcs[e + 1], s2 = srcs[e + 2], s3 = srcs[e + 3];
        int s4 = srcs[e + 4], s5 = srcs[e + 5], s6 = srcs[e + 6], s7 = srcs[e + 7];
        float v0 = __half2float(hw1h[(size_t)s0 * 32 + k]);
        float v1 = __half2float(hw1h[(size_t)s1 * 32 + k]);
        float v2 = __half2float(hw1h[(size_t)s2 * 32 + k]);
        float v3 = __half2float(hw1h[(size_t)s3 * 32 + k]);
        float v4 = __half2float(hw1h[(size_t)s4 * 32 + k]);
        float v5 = __half2float(hw1h[(size_t)s5 * 32 + k]);
        float v6 = __half2float(hw1h[(size_t)s6 * 32 + k]);
        float v7 = __half2float(hw1h[(size_t)s7 * 32 + k]);
        acc += ((v0 + v1) + (v2 + v3)) + ((v4 + v5) + (v6 + v7));
    }
    for (; e < end; ++e)
        acc += __half2float(hw1h[(size_t)srcs[e] * 32 + k]);
    float dn = dis[node];
    float self = __half2float(hw1h[(size_t)node * 32 + k]);
    float h = fmaxf(dn * (acc + self) + b1[k], 0.f);
    h1h[(size_t)node * 32 + k] = __float2half(h);
}

// ---- gemm2: hw2s = (h1 @ w2) * dis   [N,32]x[32,16] -> [N,16] f32
__global__ __launch_bounds__(256) void gemm2_kernel(const __half* __restrict__ h1h,
                                                    const float* __restrict__ w2,
                                                    const float* __restrict__ dis,
                                                    float* __restrict__ hw2s, int n) {
    __shared__ float w2s[512];
    __shared__ float h1s[16][33];
    int tid = threadIdx.x;
    for (int t = tid; t < 512; t += 256) w2s[t] = w2[t];
    int node0 = blockIdx.x * 16;
    for (int t = tid; t < 512; t += 256) {
        int r = t >> 5, c = t & 31;
        int nd = node0 + r;
        h1s[r][c] = (nd < n) ? __half2float(h1h[(size_t)nd * 32 + c]) : 0.f;
    }
    __syncthreads();
    int r = tid >> 4, j = tid & 15;
    int nd = node0 + r;
    if (nd < n) {
        float a = 0.f;
        #pragma unroll
        for (int c = 0; c < 32; ++c) a += h1s[r][c] * w2s[c * 16 + j];
        hw2s[(size_t)nd * 16 + j] = a * dis[nd];
    }
}

// ---- gatherG2: layer-2 aggregation for SELECTED nodes only (16 lanes/node)
__global__ __launch_bounds__(256) void gatherG2_kernel(const float* __restrict__ hw2s,
                                                       const float* __restrict__ dis,
                                                       const int* __restrict__ srcs,
                                                       const int* __restrict__ noffs,
                                                       const int* __restrict__ nodes,
                                                       const float* __restrict__ b2,
                                                       float* __restrict__ h2, int nsel, int n) {
    int tid = threadIdx.x;
    int slot = tid >> 4, j = tid & 15;
    int i = blockIdx.x * 16 + slot;
    if (i >= nsel) return;
    int node = nodes[i];
    int off = noffs[node], end = noffs[node + 1];
    float acc = 0.f;
    int e = off;
    for (; e + 4 <= end; e += 4) {
        int s0 = srcs[e], s1 = srcs[e + 1], s2 = srcs[e + 2], s3 = srcs[e + 3];
        float v0 = hw2s[(size_t)s0 * 16 + j];
        float v1 = hw2s[(size_t)s1 * 16 + j];
        float v2 = hw2s[(size_t)s2 * 16 + j];
        float v3 = hw2s[(size_t)s3 * 16 + j];
        acc += (v0 + v1) + (v2 + v3);
    }
    for (; e < end; ++e) acc += hw2s[(size_t)srcs[e] * 16 + j];
    h2[(size_t)node * 16 + j] = dis[node] * (acc + hw2s[(size_t)node * 16 + j]) + b2[j];
}

// ---- pairwise concat + MoE1 + MoE2 + log_softmax
__global__ __launch_bounds__(256) void pair_moe_kernel(const float* __restrict__ h2,
                                                       const int* __restrict__ nodes,
                                                       const float* __restrict__ gate1_w,
                                                       const float* __restrict__ e1_w,
                                                       const float* __restrict__ e1_b,
                                                       const float* __restrict__ gate2_w,
                                                       const float* __restrict__ e2_w,
                                                       const float* __restrict__ e2_b,
                                                       float* __restrict__ out1,
                                                       float* __restrict__ out2, int M) {
    __shared__ float hjs[50 * 16];
    __shared__ float g1s[32 * 4];
    __shared__ float e1ws[4 * 32 * 16];
    __shared__ float e1bs[4 * 16];
    __shared__ float g2s[16 * 4];
    __shared__ float e2ws[4 * 16 * 2];
    __shared__ float e2bs[4 * 2];
    int tid = threadIdx.x;
    for (int t = tid; t < 800; t += 256) { int j = t >> 4, c = t & 15; hjs[t] = h2[nodes[j] * 16 + c]; }
    for (int t = tid; t < 128; t += 256) g1s[t] = gate1_w[t];
    for (int t = tid; t < 2048; t += 256) e1ws[t] = e1_w[t];
    for (int t = tid; t < 64; t += 256) e1bs[t] = e1_b[t];
    for (int t = tid; t < 64; t += 256) g2s[t] = gate2_w[t];
    for (int t = tid; t < 128; t += 256) e2ws[t] = e2_w[t];
    if (tid < 8) e2bs[tid] = e2_b[tid];
    __syncthreads();

    int m = blockIdx.x * 256 + tid;
    if (m >= M) return;
    int i = m / 50, j = m - i * 50;

    float xs[32];
    int ni = nodes[i];
    float4 a0 = *(const float4*)&h2[ni * 16];
    float4 a1 = *(const float4*)&h2[ni * 16 + 4];
    float4 a2 = *(const float4*)&h2[ni * 16 + 8];
    float4 a3 = *(const float4*)&h2[ni * 16 + 12];
    xs[0]=a0.x; xs[1]=a0.y; xs[2]=a0.z; xs[3]=a0.w;
    xs[4]=a1.x; xs[5]=a1.y; xs[6]=a1.z; xs[7]=a1.w;
    xs[8]=a2.x; xs[9]=a2.y; xs[10]=a2.z; xs[11]=a2.w;
    xs[12]=a3.x; xs[13]=a3.y; xs[14]=a3.z; xs[15]=a3.w;
    #pragma unroll
    for (int c = 0; c < 16; ++c) xs[16 + c] = hjs[j * 16 + c];

    #pragma unroll
    for (int c = 0; c < 32; c += 4)
        *(float4*)&out2[(size_t)m * 32 + c] = make_float4(xs[c], xs[c+1], xs[c+2], xs[c+3]);

    float g[4] = {0.f, 0.f, 0.f, 0.f};
    #pragma unroll
    for (int c = 0; c < 32; ++c) {
        float xv = xs[c];
        #pragma unroll
        for (int e = 0; e < 4; ++e) g[e] += xv * g1s[c * 4 + e];
    }
    int idx = 0; float best = g[0];
    #pragma unroll
    for (int e = 1; e < 4; ++e) if (g[e] > best) { best = g[e]; idx = e; }
    float z[16];
    #pragma unroll
    for (int o = 0; o < 16; ++o) {
        float a = e1bs[idx * 16 + o];
        #pragma unroll
        for (int c = 0; c < 32; ++c) a += xs[c] * e1ws[(idx * 32 + c) * 16 + o];
        z[o] = fmaxf(a, 0.f);
    }

    float g2[4] = {0.f, 0.f, 0.f, 0.f};
    #pragma unroll
    for (int c = 0; c < 16; ++c) {
        float zv = z[c];
        #pragma unroll
        for (int e = 0; e < 4; ++e) g2[e] += zv * g2s[c * 4 + e];
    }
    int idx2 = 0; float best2 = g2[0];
    #pragma unroll
    for (int e = 1; e < 4; ++e) if (g2[e] > best2) { best2 = g2[e]; idx2 = e; }
    float z2[2];
    #pragma unroll
    for (int o = 0; o < 2; ++o) {
        float a = e2bs[idx2 * 2 + o];
        #pragma unroll
        for (int c = 0; c < 16; ++c) a += z[c] * e2ws[(idx2 * 16 + c) * 2 + o];
        z2[o] = a;
    }

    float mx = fmaxf(z2[0], z2[1]);
    float l = logf(expf(z2[0] - mx) + expf(z2[1] - mx));
    out1[(size_t)m * 2 + 0] = z2[0] - mx - l;
    out1[(size_t)m * 2 + 1] = z2[1] - mx - l;
}

extern "C" void kernel_launch(void* const* d_in, const int* in_sizes, int n_in,
                              void* d_out, int out_size, void* d_ws, size_t ws_size,
                              hipStream_t stream) {
    const float* x       = (const float*)d_in[0];
    const float* w1      = (const float*)d_in[1];
    const float* b1      = (const float*)d_in[2];
    const float* w2      = (const float*)d_in[3];
    const float* b2      = (const float*)d_in[4];
    const float* gate1_w = (const float*)d_in[5];
    const float* e1_w    = (const float*)d_in[6];
    const float* e1_b    = (const float*)d_in[7];
    const float* gate2_w = (const float*)d_in[8];
    const float* e2_w    = (const float*)d_in[9];
    const float* e2_b    = (const float*)d_in[10];
    const int*   ei      = (const int*)d_in[11];
    const int*   nodes   = (const int*)d_in[12];

    const int n    = in_sizes[0] / 256;      // 100000
    const int nE   = in_sizes[11] / 2;       // 3200000
    const int nsel = in_sizes[12];           // 4096
    const int M    = nsel * 50;              // 204800
    const int nb   = (n + NPB - 1) / NPB;    // 1563

    size_t off = 0;
    auto alloc = [&](size_t bytes) -> void* {
        void* p = (char*)d_ws + off;
        off += (bytes + 255) & ~(size_t)255;
        return p;
    };
    float*  dis    = (float*)alloc((size_t)n * 4);
    int*    bhist  = (int*)alloc((size_t)nb * 4);
    int*    boffs  = (int*)alloc((size_t)(nb + 1) * 4);
    int*    gcur   = (int*)alloc((size_t)nb * 4);
    int*    noffs  = (int*)alloc((size_t)(n + 1) * 4);
    int*    keys   = (int*)alloc((size_t)nE * 4);   // becomes srcs after nodesort
    __half* hw1h   = (__half*)alloc((size_t)n * 32 * 2);
    __half* h1h    = (__half*)alloc((size_t)n * 32 * 2);
    float*  hw2s   = (float*)alloc((size_t)n * 16 * 4);
    float*  h2     = (float*)alloc((size_t)n * 16 * 4);
    if (off > ws_size) return;

    float* out1 = (float*)d_out;              // [M,2]
    float* out2 = out1 + (size_t)M * 2;       // [M,32]

    zero_kernel<<<(nb + 255) / 256, 256, 0, stream>>>(bhist, nb);
    histA_kernel<<<(nE + 4095) / 4096, 256, 0, stream>>>(ei, bhist, nE, nb);
    scanB_kernel<<<1, 256, 0, stream>>>(bhist, boffs, gcur, nb);
    scatterC_kernel<<<(nE + BATCH - 1) / BATCH, 256, 0, stream>>>(ei, gcur, keys, nE, nb);
    nodesort_kernel<<<nb, 256, 0, stream>>>(keys, boffs, noffs, dis, n, nb);
    hw1s_kernel<<<(n + 127) / 128, 256, 0, stream>>>(x, w1, dis, hw1h, n);
    gatherG1_kernel<<<(n + 7) / 8, 256, 0, stream>>>(hw1h, dis, keys, noffs, b1, h1h, n);
    gemm2_kernel<<<(n + 15) / 16, 256, 0, stream>>>(h1h, w2, dis, hw2s, n);
    gatherG2_kernel<<<(nsel + 15) / 16, 256, 0, stream>>>(hw2s, dis, keys, noffs, nodes, b2,
                                                          h2, nsel, n);
    pair_moe_kernel<<<(M + 255) / 256, 256, 0, stream>>>(h2, nodes, gate1_w, e1_w, e1_b,
                                                         gate2_w, e2_w, e2_b, out1, out2, M);
}